// Round 2
// baseline (538.387 us; speedup 1.0000x reference)
//
#include <hip/hip_runtime.h>
#include <hip/hip_bf16.h>

typedef unsigned int u32;
typedef unsigned short u16;
typedef short short8 __attribute__((ext_vector_type(8)));
typedef float f32x4 __attribute__((ext_vector_type(4)));

#define R_ 32
#define KEYS_PER_B 2048     // 2 rowgroups * 32 relations * 32 rows
#define SORT_STRIDE 1024    // fixed per-chunk slots in sorted[] (mean 767, +9 sigma)
#define CAP 20              // per-wave per-relation buffered edge gathers (lambda=12)

static __device__ __forceinline__ u16 f2bf(float f) {
  u32 u = __float_as_uint(f);
  u = (u + 0x7FFFu + ((u >> 16) & 1u)) >> 16;   // RNE
  return (u16)u;
}
static __device__ __forceinline__ u32 pk2(float a, float b) {
  __hip_bfloat162 h2 = __float22bfloat162_rn(make_float2(a, b));
  union { __hip_bfloat162 h; u32 u; } cv; cv.h = h2; return cv.u;
}

// ---- fused: x fp32->bf16 convert  +  W/W_root pack into MFMA B-fragment order ----
__global__ void k_pre(const float* __restrict__ x, const float* __restrict__ W,
                      const float* __restrict__ Wroot, u16* __restrict__ xb,
                      u16* __restrict__ wp, u16* __restrict__ wrootp,
                      int n4, int convNB) {
  if ((int)blockIdx.x < convNB) {
    int i = blockIdx.x * 256 + threadIdx.x;
    if (i >= n4) return;
    const float4 f = ((const float4*)x)[i];
    u32 lo = (u32)f2bf(f.x) | ((u32)f2bf(f.y) << 16);
    u32 hi = (u32)f2bf(f.z) | ((u32)f2bf(f.w) << 16);
    ((uint2*)xb)[i] = make_uint2(lo, hi);
  } else {
    int tid = (blockIdx.x - convNB) * 256 + threadIdx.x;
    if (tid >= 33 * 2048) return;
    int lane = tid & 63;
    int ks = (tid >> 6) & 3;
    int ct = (tid >> 8) & 7;
    int rr = tid >> 11;
    int i0 = ks * 32 + (lane >> 4) * 8;
    int o  = ct * 16 + (lane & 15);
    const float* src = (rr < 32) ? (W + (size_t)rr * (128 * 128)) : Wroot;
    u16* dst = (rr < 32) ? (wp + ((size_t)((rr * 8 + ct) * 4 + ks) * 64 + lane) * 8)
                         : (wrootp + ((size_t)((ct * 4 + ks) * 64 + lane)) * 8);
#pragma unroll
    for (int j = 0; j < 8; ++j) dst[j] = f2bf(src[(size_t)(i0 + j) * 128 + o]);
  }
}

// key = (tile, rowgroup-of-32, relation, row-in-group) -> edges for one
// (wave, relation) are contiguous and sorted by row
static __device__ __forceinline__ int sort_key(int tgt, int r) {
  return (tgt >> 6) * KEYS_PER_B + ((tgt >> 5) & 1) * 1024 + r * 32 + (tgt & 31);
}

// ---- histogram of sort keys ----
__global__ void k_hist(const int* __restrict__ ei, const int* __restrict__ et,
                       int* __restrict__ hist, int E) {
  int e = blockIdx.x * 256 + threadIdx.x;
  if (e >= E) return;
  atomicAdd(hist + sort_key(ei[E + e], et[e]), 1);
}

// ---- per-chunk exclusive scan (chunk = 2048 keys = one tile) ----
__global__ __launch_bounds__(256) void k_scan_local(const int* __restrict__ hist,
                                                    int* __restrict__ offs) {
  __shared__ int wsum[4];
  int b = blockIdx.x, t = threadIdx.x;
  size_t base = (size_t)b * KEYS_PER_B + (size_t)t * 8;
  int4 a = *(const int4*)(hist + base);
  int4 c = *(const int4*)(hist + base + 4);
  int v[8] = {a.x, a.y, a.z, a.w, c.x, c.y, c.z, c.w};
  int s = 0;
#pragma unroll
  for (int i = 0; i < 8; ++i) s += v[i];
  int lane = t & 63, w = t >> 6;
  int x = s;
#pragma unroll
  for (int off = 1; off < 64; off <<= 1) {
    int y = __shfl_up(x, off);
    if (lane >= off) x += y;
  }
  if (lane == 63) wsum[w] = x;
  __syncthreads();
  int wb = 0;
  for (int i = 0; i < w; ++i) wb += wsum[i];
  int ex = wb + x - s;
  int o[8];
#pragma unroll
  for (int i = 0; i < 8; ++i) { o[i] = ex; ex += v[i]; }
  *(int4*)(offs + base) = make_int4(o[0], o[1], o[2], o[3]);
  *(int4*)(offs + base + 4) = make_int4(o[4], o[5], o[6], o[7]);
}

// ---- scatter; offs[key] becomes per-key chunk-local END; sorted = src | row64<<16 ----
__global__ void k_scatter(const int* __restrict__ ei, const int* __restrict__ et,
                          int* __restrict__ offs, u32* __restrict__ sorted, int E) {
  int e = blockIdx.x * 256 + threadIdx.x;
  if (e >= E) return;
  int src = ei[e];
  int tgt = ei[E + e];
  int r = et[e];
  int p = atomicAdd(offs + sort_key(tgt, r), 1);
  if (p < SORT_STRIDE)
    sorted[(size_t)(tgt >> 6) * SORT_STRIDE + p] = (u32)src | ((u32)(tgt & 63) << 16);
}

// ---- main batch kernel: BARRIER-FREE, each wave fully independent ----
// Tile b = 64 nodes. Wave w = (rowgroup g = w&1) x (colhalf ch = w>>1):
// owns rows nb+g*32..+31 and cols ch*64..+63 for ALL 32 relations.
// Private LDS agg region per wave (32x136 u16) -> no __syncthreads anywhere;
// 12 independent wave-streams per CU hide the gather latency chains.
// Per relation: consume prefetched xv -> LDS rows (run detection);
// issue bfr(r) loads BEFORE xv(r+1) gathers (in-order vmcnt retirement:
// MFMA then waits only on bfr; gather latency hides under GEMM(r)).
__global__ __launch_bounds__(256, 3) void k_batch(
    const u16* __restrict__ xb, const u16* __restrict__ wp, const u16* __restrict__ wrootp,
    const float* __restrict__ bias, const u32* __restrict__ sorted,
    const int* __restrict__ offs, float* __restrict__ h, int N) {
  __shared__ u16 aggb[4][32 * 136];   // 34.8 KB, one private region per wave
  const int b = blockIdx.x, t = threadIdx.x;
  const int lane = t & 63, w = t >> 6;
  const int g = w & 1;     // rowgroup (32 rows)
  const int ch = w >> 1;   // colhalf (64 cols)
  const int m = lane & 15, q = lane >> 4;
  const int nb = b * 64;
  const int keyBase = b * KEYS_PER_B;
  const int wkBase = keyBase + g * 1024;
  const u32* srt = sorted + (size_t)b * SORT_STRIDE;
  u16* agg = aggb[w];

  const int nEdge = offs[keyBase + KEYS_PER_B - 1];
  const int clampP = (nEdge > 0) ? nEdge - 1 : 0;
  int sCur = (g == 0) ? 0 : offs[keyBase + 1023];   // start of (g, rel 0), chunk-local
  int eCur = offs[wkBase + 31];                     // end of rel 0
  int eNext = offs[wkBase + 63];                    // end of rel 1

  const short8 zero8 = {0, 0, 0, 0, 0, 0, 0, 0};
  f32x4 acc[2][4];
#pragma unroll
  for (int rt = 0; rt < 2; ++rt)
#pragma unroll
    for (int c = 0; c < 4; ++c) acc[rt][c] = (f32x4){0.f, 0.f, 0.f, 0.f};

  // root GEMM for this wave's quadrant (issued before gathers: keeps its
  // vmem waits independent of the gather chain)
#pragma unroll
  for (int ks = 0; ks < 4; ++ks) {
    const int kb = ks * 32 + q * 8;
    short8 af[2];
#pragma unroll
    for (int rt = 0; rt < 2; ++rt) {
      int node = nb + g * 32 + rt * 16 + m;
      af[rt] = (node < N) ? *(const short8*)(xb + (size_t)node * 128 + kb) : zero8;
    }
#pragma unroll
    for (int c = 0; c < 4; ++c) {
      short8 bf = *(const short8*)(wrootp + ((size_t)(((ch * 4 + c) * 4 + ks) * 64 + lane)) * 8);
#pragma unroll
      for (int rt = 0; rt < 2; ++rt)
        acc[rt][c] = __builtin_amdgcn_mfma_f32_16x16x32_bf16(af[rt], bf, acc[rt][c], 0, 0, 0);
    }
  }

  // prologue: issue gathers for relation 0
  u32 ev;
  {
    int pc = sCur + lane;                 // lane (not m): covers CAP up to 64
    if (pc > clampP) pc = clampP;
    ev = srt[pc];
  }
  u32 xv[CAP];
  {
    const int nB = min(eCur - sCur, CAP);
#pragma unroll
    for (int j = 0; j < CAP; ++j) {
      if (j < nB) {
        int e = __builtin_amdgcn_readlane((int)ev, j);
        xv[j] = *(const u32*)(xb + (size_t)(e & 0xFFFF) * 128 + 2 * lane);
      }
    }
  }

  for (int r = 0; r < R_; ++r) {
    // ---- build(r): zero own rows, consume buffer with run detection ----
#pragma unroll
    for (int rr = 0; rr < 32; ++rr)
      *(u32*)(agg + (size_t)rr * 136 + 2 * lane) = 0;

    {
      const int nB = min(eCur - sCur, CAP);
      int curRow = -1, rc = 0;
      float v0 = 0.f, v1 = 0.f;
#pragma unroll
      for (int j = 0; j < CAP; ++j) {
        if (j < nB) {
          int e = __builtin_amdgcn_readlane((int)ev, j);
          int tl = (e >> 16) & 31;
          if (tl != curRow) {
            if (rc > 0) {
              float sc = 1.0f / (float)rc;
              *(u32*)(agg + (size_t)curRow * 136 + 2 * lane) = pk2(v0 * sc, v1 * sc);
            }
            curRow = tl; v0 = 0.f; v1 = 0.f; rc = 0;
          }
          v0 += __uint_as_float(xv[j] << 16);
          v1 += __uint_as_float(xv[j] & 0xFFFF0000u);
          ++rc;
        }
      }
      // rare overflow tail (cnt > CAP): serial loads
      for (int p = sCur + CAP; p < eCur; ++p) {
        u32 e = srt[p];
        u32 xvv = *(const u32*)(xb + (size_t)(e & 0xFFFFu) * 128 + 2 * lane);
        int tl = (int)((e >> 16) & 31);
        if (tl != curRow) {
          if (rc > 0) {
            float sc = 1.0f / (float)rc;
            *(u32*)(agg + (size_t)curRow * 136 + 2 * lane) = pk2(v0 * sc, v1 * sc);
          }
          curRow = tl; v0 = 0.f; v1 = 0.f; rc = 0;
        }
        v0 += __uint_as_float(xvv << 16);
        v1 += __uint_as_float(xvv & 0xFFFF0000u);
        ++rc;
      }
      if (rc > 0) {
        float sc = 1.0f / (float)rc;
        *(u32*)(agg + (size_t)curRow * 136 + 2 * lane) = pk2(v0 * sc, v1 * sc);
      }
    }

    // ---- bfr(r) loads FIRST (oldest vmem -> MFMA waits only on these) ----
    short8 bfr[4][4];
#pragma unroll
    for (int ks = 0; ks < 4; ++ks)
#pragma unroll
      for (int c = 0; c < 4; ++c)
        bfr[ks][c] = *(const short8*)(wp + ((size_t)(((r * 8 + ch * 4 + c) * 4 + ks) * 64 + lane)) * 8);

    // ---- issue gathers for r+1 (latency hides under GEMM(r)) ----
    if (r < R_ - 1) {
      const int sN = eCur;
      const int eN = eNext;
      int pc = sN + lane;
      if (pc > clampP) pc = clampP;
      ev = srt[pc];
      const int nBn = min(eN - sN, CAP);
#pragma unroll
      for (int j = 0; j < CAP; ++j) {
        if (j < nBn) {
          int e = __builtin_amdgcn_readlane((int)ev, j);
          xv[j] = *(const u32*)(xb + (size_t)(e & 0xFFFF) * 128 + 2 * lane);
        }
      }
      if (r < R_ - 2) eNext = offs[wkBase + (r + 2) * 32 + 31];
      sCur = sN; eCur = eN;
    }

    // ---- GEMM(r): acc += agg @ W[r] (af from private LDS region) ----
#pragma unroll
    for (int ks = 0; ks < 4; ++ks) {
      const int kb = ks * 32 + q * 8;
      short8 af[2];
#pragma unroll
      for (int rt = 0; rt < 2; ++rt)
        af[rt] = *(const short8*)(agg + (size_t)(rt * 16 + m) * 136 + kb);
#pragma unroll
      for (int c = 0; c < 4; ++c)
#pragma unroll
        for (int rt = 0; rt < 2; ++rt)
          acc[rt][c] = __builtin_amdgcn_mfma_f32_16x16x32_bf16(af[rt], bfr[ks][c], acc[rt][c], 0, 0, 0);
    }
  }

  // ---- epilogue: bias + relu + store h (fp32) ----
#pragma unroll
  for (int c = 0; c < 4; ++c) {
    const int col = (ch * 4 + c) * 16 + m;
    const float bv = bias[col];
#pragma unroll
    for (int rt = 0; rt < 2; ++rt) {
#pragma unroll
      for (int gg = 0; gg < 4; ++gg) {
        const int row = nb + g * 32 + rt * 16 + q * 4 + gg;
        if (row < N) {
          float v = acc[rt][c][gg] + bv;
          h[(size_t)row * 128 + col] = v > 0.f ? v : 0.f;
        }
      }
    }
  }
}

// ---- DistMult scoring: one wave per triplet, float2 loads ----
__global__ void k_score(const float* __restrict__ h, const float* __restrict__ rel_emb,
                        const int* __restrict__ head, const int* __restrict__ tail,
                        const int* __restrict__ rel, float* __restrict__ out, int T) {
  int lane = threadIdx.x & 63, w = threadIdx.x >> 6;
  int gid = blockIdx.x * 4 + w;
  if (gid >= T) return;
  const float2 h2 = *(const float2*)(h + (size_t)head[gid] * 128 + 2 * lane);
  const float2 t2 = *(const float2*)(h + (size_t)tail[gid] * 128 + 2 * lane);
  const float2 r2 = *(const float2*)(rel_emb + (size_t)rel[gid] * 128 + 2 * lane);
  float s = h2.x * r2.x * t2.x + h2.y * r2.y * t2.y;
#pragma unroll
  for (int off = 32; off > 0; off >>= 1) s += __shfl_down(s, off);
  if (lane == 0) out[gid] = s;
}

extern "C" void kernel_launch(void* const* d_in, const int* in_sizes, int n_in,
                              void* d_out, int out_size, void* d_ws, size_t ws_size,
                              hipStream_t stream) {
  const float* x     = (const float*)d_in[0];
  const float* W     = (const float*)d_in[1];
  const float* Wroot = (const float*)d_in[2];
  const float* bias  = (const float*)d_in[3];
  const float* relE  = (const float*)d_in[4];
  const int* ei      = (const int*)d_in[5];
  const int* et      = (const int*)d_in[6];
  const int* headI   = (const int*)d_in[7];
  const int* tailI   = (const int*)d_in[8];
  const int* relI    = (const int*)d_in[9];
  float* out = (float*)d_out;

  const int N = in_sizes[0] / 128;   // 50000
  const int E = in_sizes[6];         // 600000
  const int T = in_sizes[7];         // 8192
  const int NB = (N + 63) >> 6;      // 782
  const int NKEYS = NB * KEYS_PER_B;

  char* p = (char*)d_ws;
  auto alloc = [&](size_t bytes) -> void* {
    void* r = (void*)p;
    p += (bytes + 255) & ~(size_t)255;
    return r;
  };
  u16* xb     = (u16*)alloc((size_t)N * 128 * 2);        // 12.8 MB
  u16* wp     = (u16*)alloc((size_t)32 * 2048 * 8 * 2);  // 1 MB
  u16* wrootp = (u16*)alloc((size_t)2048 * 8 * 2);
  int* hist   = (int*)alloc((size_t)NKEYS * 4);          // 6.4 MB
  int* offs   = (int*)alloc((size_t)NKEYS * 4);          // 6.4 MB
  u32* sorted = (u32*)alloc((size_t)NB * SORT_STRIDE * 4); // 3.2 MB
  float* h    = (float*)alloc((size_t)N * 128 * 4);      // 25.6 MB

  const int n4 = N * 128 / 4;
  const int convNB = (n4 + 255) / 256;
  const int packNB = (33 * 2048 + 255) / 256;

  hipMemsetAsync(hist, 0, (size_t)NKEYS * 4, stream);
  k_pre<<<convNB + packNB, 256, 0, stream>>>(x, W, Wroot, xb, wp, wrootp, n4, convNB);
  k_hist<<<(E + 255) / 256, 256, 0, stream>>>(ei, et, hist, E);
  k_scan_local<<<NB, 256, 0, stream>>>(hist, offs);
  k_scatter<<<(E + 255) / 256, 256, 0, stream>>>(ei, et, offs, sorted, E);
  k_batch<<<NB, 256, 0, stream>>>(xb, wp, wrootp, bias, sorted, offs, h, N);
  k_score<<<(T + 3) / 4, 256, 0, stream>>>(h, relE, headI, tailI, relI, out, T);
}

// Round 3
// 418.748 us; speedup vs baseline: 1.2857x; 1.2857x over previous
//
#include <hip/hip_runtime.h>
#include <hip/hip_bf16.h>

typedef unsigned int u32;
typedef unsigned short u16;
typedef short short8 __attribute__((ext_vector_type(8)));
typedef float f32x4 __attribute__((ext_vector_type(4)));

#define R_ 32
#define KEYS_PER_B 2048     // 4 wavegroups * 32 relations * 16 rows
#define SORT_STRIDE 1024    // fixed per-chunk slots in sorted[] (mean 767, +9 sigma)
#define CAP 24              // per-wave per-PAIR buffered edge gathers (lambda=12)
#define PH 16               // relation pairs per block

static __device__ __forceinline__ u16 f2bf(float f) {
  u32 u = __float_as_uint(f);
  u = (u + 0x7FFFu + ((u >> 16) & 1u)) >> 16;   // RNE
  return (u16)u;
}
static __device__ __forceinline__ u32 pk2(float a, float b) {
  __hip_bfloat162 h2 = __float22bfloat162_rn(make_float2(a, b));
  union { __hip_bfloat162 h; u32 u; } cv; cv.h = h2; return cv.u;
}

// ---- fused: x fp32->bf16 convert  +  W/W_root pack into MFMA B-fragment order ----
__global__ void k_pre(const float* __restrict__ x, const float* __restrict__ W,
                      const float* __restrict__ Wroot, u16* __restrict__ xb,
                      u16* __restrict__ wp, u16* __restrict__ wrootp,
                      int n4, int convNB) {
  if ((int)blockIdx.x < convNB) {
    int i = blockIdx.x * 256 + threadIdx.x;
    if (i >= n4) return;
    const float4 f = ((const float4*)x)[i];
    u32 lo = (u32)f2bf(f.x) | ((u32)f2bf(f.y) << 16);
    u32 hi = (u32)f2bf(f.z) | ((u32)f2bf(f.w) << 16);
    ((uint2*)xb)[i] = make_uint2(lo, hi);
  } else {
    int tid = (blockIdx.x - convNB) * 256 + threadIdx.x;
    if (tid >= 33 * 2048) return;
    int lane = tid & 63;
    int ks = (tid >> 6) & 3;
    int ct = (tid >> 8) & 7;
    int rr = tid >> 11;
    int i0 = ks * 32 + (lane >> 4) * 8;
    int o  = ct * 16 + (lane & 15);
    const float* src = (rr < 32) ? (W + (size_t)rr * (128 * 128)) : Wroot;
    u16* dst = (rr < 32) ? (wp + ((size_t)((rr * 8 + ct) * 4 + ks) * 64 + lane) * 8)
                         : (wrootp + ((size_t)((ct * 4 + ks) * 64 + lane)) * 8);
#pragma unroll
    for (int j = 0; j < 8; ++j) dst[j] = f2bf(src[(size_t)(i0 + j) * 128 + o]);
  }
}

// key = (tile, wavegroup-of-16, relation, row-in-group)
static __device__ __forceinline__ int sort_key(int tgt, int r) {
  return (tgt >> 6) * KEYS_PER_B + ((tgt >> 4) & 3) * 512 + r * 16 + (tgt & 15);
}

// ---- histogram of sort keys ----
__global__ void k_hist(const int* __restrict__ ei, const int* __restrict__ et,
                       int* __restrict__ hist, int E) {
  int e = blockIdx.x * 256 + threadIdx.x;
  if (e >= E) return;
  atomicAdd(hist + sort_key(ei[E + e], et[e]), 1);
}

// ---- per-chunk exclusive scan (chunk = 2048 keys = one batch) ----
__global__ __launch_bounds__(256) void k_scan_local(const int* __restrict__ hist,
                                                    int* __restrict__ offs) {
  __shared__ int wsum[4];
  int b = blockIdx.x, t = threadIdx.x;
  size_t base = (size_t)b * KEYS_PER_B + (size_t)t * 8;
  int4 a = *(const int4*)(hist + base);
  int4 c = *(const int4*)(hist + base + 4);
  int v[8] = {a.x, a.y, a.z, a.w, c.x, c.y, c.z, c.w};
  int s = 0;
#pragma unroll
  for (int i = 0; i < 8; ++i) s += v[i];
  int lane = t & 63, w = t >> 6;
  int x = s;
#pragma unroll
  for (int off = 1; off < 64; off <<= 1) {
    int y = __shfl_up(x, off);
    if (lane >= off) x += y;
  }
  if (lane == 63) wsum[w] = x;
  __syncthreads();
  int wb = 0;
  for (int i = 0; i < w; ++i) wb += wsum[i];
  int ex = wb + x - s;
  int o[8];
#pragma unroll
  for (int i = 0; i < 8; ++i) { o[i] = ex; ex += v[i]; }
  *(int4*)(offs + base) = make_int4(o[0], o[1], o[2], o[3]);
  *(int4*)(offs + base + 4) = make_int4(o[4], o[5], o[6], o[7]);
}

// ---- scatter; offs[key] becomes per-key chunk-local END; sorted = src | row64<<16 ----
__global__ void k_scatter(const int* __restrict__ ei, const int* __restrict__ et,
                          int* __restrict__ offs, u32* __restrict__ sorted, int E) {
  int e = blockIdx.x * 256 + threadIdx.x;
  if (e >= E) return;
  int src = ei[e];
  int tgt = ei[E + e];
  int r = et[e];
  int p = atomicAdd(offs + sort_key(tgt, r), 1);
  if (p < SORT_STRIDE)
    sorted[(size_t)(tgt >> 6) * SORT_STRIDE + p] = (u32)src | ((u32)(tgt & 63) << 16);
}

// ---- main batch kernel: 2 relations fused per phase ----
// Wave w owns rows w*16..w*16+15. Phase i handles relations 2i,2i+1; their
// edges are contiguous in sorted. Extended run key = row + 64*(second rel);
// aggb is [128][136] (rows 0..63 = rel 2i, 64..127 = rel 2i+1).
// Per phase: build(zero 32 rows + consume combined range) / barrier /
//   load b0,b1 W-fragments (oldest vmem), issue gathers for next pair,
//   prefetch offs for pair i+2, GEMM(2i) then GEMM(2i+1) / barrier.
// In-order vmcnt retirement: GEMMs wait only on b0/b1; next-pair gather
// latency hides under both GEMMs + barrier + zero-loop.
__global__ __launch_bounds__(256) void k_batch(
    const u16* __restrict__ xb, const u16* __restrict__ wp, const u16* __restrict__ wrootp,
    const float* __restrict__ bias, const u32* __restrict__ sorted,
    const int* __restrict__ offs, float* __restrict__ h, int N) {
  __shared__ u16 aggb[128 * 136];   // 34.8 KB
  const int b = blockIdx.x, t = threadIdx.x;
  const int lane = t & 63, w = t >> 6;
  const int m = lane & 15, q = lane >> 4;
  const int nb = b * 64;
  const int keyBase = b * KEYS_PER_B;
  const int wkBase = keyBase + w * 512;
  const u32* srt = sorted + (size_t)b * SORT_STRIDE;

  const int nEdge = offs[keyBase + KEYS_PER_B - 1];
  const int clampP = (nEdge > 0) ? nEdge - 1 : 0;
  int sCur = (w == 0) ? 0 : offs[wkBase - 1];   // start of pair 0 (chunk-local)
  int eMid = offs[wkBase + 15];                 // end of rel 0
  int eCur = offs[wkBase + 31];                 // end of rel 1 (= end of pair 0)
  int nMid = offs[wkBase + 47];                 // pair 1 bounds
  int nEnd = offs[wkBase + 63];

  // prologue: issue gathers for pair 0 (overlap root GEMM)
  u32 ev;
  {
    int pc = sCur + lane;
    if (pc > clampP) pc = clampP;
    ev = srt[pc];
  }
  u32 xv[CAP];
  {
    const int nB = min(eCur - sCur, CAP);
#pragma unroll
    for (int j = 0; j < CAP; ++j) {
      if (j < nB) {
        int e = __builtin_amdgcn_readlane((int)ev, j);
        xv[j] = *(const u32*)(xb + (size_t)(e & 0xFFFF) * 128 + 2 * lane);
      }
    }
  }

  const short8 zero8 = {0, 0, 0, 0, 0, 0, 0, 0};
  f32x4 acc[4][2];
#pragma unroll
  for (int rt = 0; rt < 4; ++rt)
#pragma unroll
    for (int c = 0; c < 2; ++c) acc[rt][c] = (f32x4){0.f, 0.f, 0.f, 0.f};
  const int wct0 = w * 2;

  // root GEMM: acc += x_batch @ W_root
#pragma unroll
  for (int ks = 0; ks < 4; ++ks) {
    const int kb = ks * 32 + q * 8;
    short8 af[4];
#pragma unroll
    for (int rt = 0; rt < 4; ++rt) {
      int node = nb + rt * 16 + m;
      af[rt] = (node < N) ? *(const short8*)(xb + (size_t)node * 128 + kb) : zero8;
    }
#pragma unroll
    for (int c = 0; c < 2; ++c) {
      short8 bf = *(const short8*)(wrootp + ((size_t)(((wct0 + c) * 4 + ks) * 64 + lane)) * 8);
#pragma unroll
      for (int rt = 0; rt < 4; ++rt)
        acc[rt][c] = __builtin_amdgcn_mfma_f32_16x16x32_bf16(af[rt], bf, acc[rt][c], 0, 0, 0);
    }
  }
  __syncthreads();

  for (int i = 0; i < PH; ++i) {
    // ---- build: zero own 2x16 rows, consume combined pair range ----
#pragma unroll
    for (int rr = 0; rr < 16; ++rr) {
      *(u32*)(aggb + (size_t)(w * 16 + rr) * 136 + 2 * lane) = 0;
      *(u32*)(aggb + (size_t)(64 + w * 16 + rr) * 136 + 2 * lane) = 0;
    }

    {
      const int jB = eMid - sCur;              // wave-uniform rel boundary (j-space)
      const int nB = min(eCur - sCur, CAP);
      int curRow = -1, rc = 0;
      float v0 = 0.f, v1 = 0.f;
#pragma unroll
      for (int j = 0; j < CAP; ++j) {
        if (j < nB) {
          int e = __builtin_amdgcn_readlane((int)ev, j);
          int ek = ((e >> 16) & 63) + ((j >= jB) ? 64 : 0);
          if (ek != curRow) {
            if (rc > 0) {
              float sc = __builtin_amdgcn_rcpf((float)rc);
              *(u32*)(aggb + (size_t)curRow * 136 + 2 * lane) = pk2(v0 * sc, v1 * sc);
            }
            curRow = ek; v0 = 0.f; v1 = 0.f; rc = 0;
          }
          v0 += __uint_as_float(xv[j] << 16);
          v1 += __uint_as_float(xv[j] & 0xFFFF0000u);
          ++rc;
        }
      }
      // rare overflow tail (cnt > CAP): serial loads
      for (int p = sCur + CAP; p < eCur; ++p) {
        u32 e = srt[p];
        u32 xvv = *(const u32*)(xb + (size_t)(e & 0xFFFFu) * 128 + 2 * lane);
        int ek = (int)((e >> 16) & 63) + ((p >= eMid) ? 64 : 0);
        if (ek != curRow) {
          if (rc > 0) {
            float sc = __builtin_amdgcn_rcpf((float)rc);
            *(u32*)(aggb + (size_t)curRow * 136 + 2 * lane) = pk2(v0 * sc, v1 * sc);
          }
          curRow = ek; v0 = 0.f; v1 = 0.f; rc = 0;
        }
        v0 += __uint_as_float(xvv << 16);
        v1 += __uint_as_float(xvv & 0xFFFF0000u);
        ++rc;
      }
      if (rc > 0) {
        float sc = __builtin_amdgcn_rcpf((float)rc);
        *(u32*)(aggb + (size_t)curRow * 136 + 2 * lane) = pk2(v0 * sc, v1 * sc);
      }
    }
    __syncthreads();

    // ---- phase A ----
    // W fragments for BOTH relations first (oldest vmem -> GEMMs wait only here)
    const int r0 = 2 * i;
    short8 b0[4][2], b1[4][2];
#pragma unroll
    for (int ks = 0; ks < 4; ++ks)
#pragma unroll
      for (int c = 0; c < 2; ++c) {
        b0[ks][c] = *(const short8*)(wp + ((size_t)(((r0 * 8 + wct0 + c) * 4 + ks) * 64 + lane)) * 8);
        b1[ks][c] = *(const short8*)(wp + ((size_t)((((r0 + 1) * 8 + wct0 + c) * 4 + ks) * 64 + lane)) * 8);
      }

    // issue gathers for pair i+1 (latency hides under both GEMMs)
    if (i < PH - 1) {
      const int sN = eCur;
      int pc = sN + lane;
      if (pc > clampP) pc = clampP;
      ev = srt[pc];
      const int nBn = min(nEnd - sN, CAP);
#pragma unroll
      for (int j = 0; j < CAP; ++j) {
        if (j < nBn) {
          int e = __builtin_amdgcn_readlane((int)ev, j);
          xv[j] = *(const u32*)(xb + (size_t)(e & 0xFFFF) * 128 + 2 * lane);
        }
      }
      sCur = sN; eMid = nMid; eCur = nEnd;
      if (i < PH - 2) {
        nMid = offs[wkBase + (i + 2) * 32 + 15];
        nEnd = offs[wkBase + (i + 2) * 32 + 31];
      }
    }

    // GEMM(2i): acc += agg[0..63] @ W[2i]
#pragma unroll
    for (int ks = 0; ks < 4; ++ks) {
      const int kb = ks * 32 + q * 8;
      short8 af[4];
#pragma unroll
      for (int rt = 0; rt < 4; ++rt)
        af[rt] = *(const short8*)(aggb + (size_t)(rt * 16 + m) * 136 + kb);
#pragma unroll
      for (int c = 0; c < 2; ++c)
#pragma unroll
        for (int rt = 0; rt < 4; ++rt)
          acc[rt][c] = __builtin_amdgcn_mfma_f32_16x16x32_bf16(af[rt], b0[ks][c], acc[rt][c], 0, 0, 0);
    }
    // GEMM(2i+1): acc += agg[64..127] @ W[2i+1]
#pragma unroll
    for (int ks = 0; ks < 4; ++ks) {
      const int kb = ks * 32 + q * 8;
      short8 af[4];
#pragma unroll
      for (int rt = 0; rt < 4; ++rt)
        af[rt] = *(const short8*)(aggb + (size_t)(64 + rt * 16 + m) * 136 + kb);
#pragma unroll
      for (int c = 0; c < 2; ++c)
#pragma unroll
        for (int rt = 0; rt < 4; ++rt)
          acc[rt][c] = __builtin_amdgcn_mfma_f32_16x16x32_bf16(af[rt], b1[ks][c], acc[rt][c], 0, 0, 0);
    }
    __syncthreads();
  }

  // ---- epilogue: bias + relu + store h (fp32) ----
#pragma unroll
  for (int c = 0; c < 2; ++c) {
    const int col = (wct0 + c) * 16 + m;
    const float bv = bias[col];
#pragma unroll
    for (int rt = 0; rt < 4; ++rt) {
#pragma unroll
      for (int g = 0; g < 4; ++g) {
        const int row = nb + rt * 16 + q * 4 + g;
        if (row < N) {
          float v = acc[rt][c][g] + bv;
          h[(size_t)row * 128 + col] = v > 0.f ? v : 0.f;
        }
      }
    }
  }
}

// ---- DistMult scoring: one wave per triplet, float2 loads ----
__global__ void k_score(const float* __restrict__ h, const float* __restrict__ rel_emb,
                        const int* __restrict__ head, const int* __restrict__ tail,
                        const int* __restrict__ rel, float* __restrict__ out, int T) {
  int lane = threadIdx.x & 63, w = threadIdx.x >> 6;
  int gid = blockIdx.x * 4 + w;
  if (gid >= T) return;
  const float2 h2 = *(const float2*)(h + (size_t)head[gid] * 128 + 2 * lane);
  const float2 t2 = *(const float2*)(h + (size_t)tail[gid] * 128 + 2 * lane);
  const float2 r2 = *(const float2*)(rel_emb + (size_t)rel[gid] * 128 + 2 * lane);
  float s = h2.x * r2.x * t2.x + h2.y * r2.y * t2.y;
#pragma unroll
  for (int off = 32; off > 0; off >>= 1) s += __shfl_down(s, off);
  if (lane == 0) out[gid] = s;
}

extern "C" void kernel_launch(void* const* d_in, const int* in_sizes, int n_in,
                              void* d_out, int out_size, void* d_ws, size_t ws_size,
                              hipStream_t stream) {
  const float* x     = (const float*)d_in[0];
  const float* W     = (const float*)d_in[1];
  const float* Wroot = (const float*)d_in[2];
  const float* bias  = (const float*)d_in[3];
  const float* relE  = (const float*)d_in[4];
  const int* ei      = (const int*)d_in[5];
  const int* et      = (const int*)d_in[6];
  const int* headI   = (const int*)d_in[7];
  const int* tailI   = (const int*)d_in[8];
  const int* relI    = (const int*)d_in[9];
  float* out = (float*)d_out;

  const int N = in_sizes[0] / 128;   // 50000
  const int E = in_sizes[6];         // 600000
  const int T = in_sizes[7];         // 8192
  const int NB = (N + 63) >> 6;      // 782
  const int NKEYS = NB * KEYS_PER_B;

  char* p = (char*)d_ws;
  auto alloc = [&](size_t bytes) -> void* {
    void* r = (void*)p;
    p += (bytes + 255) & ~(size_t)255;
    return r;
  };
  u16* xb     = (u16*)alloc((size_t)N * 128 * 2);        // 12.8 MB
  u16* wp     = (u16*)alloc((size_t)32 * 2048 * 8 * 2);  // 1 MB
  u16* wrootp = (u16*)alloc((size_t)2048 * 8 * 2);
  int* hist   = (int*)alloc((size_t)NKEYS * 4);          // 6.4 MB
  int* offs   = (int*)alloc((size_t)NKEYS * 4);          // 6.4 MB
  u32* sorted = (u32*)alloc((size_t)NB * SORT_STRIDE * 4); // 3.2 MB
  float* h    = (float*)alloc((size_t)N * 128 * 4);      // 25.6 MB

  const int n4 = N * 128 / 4;
  const int convNB = (n4 + 255) / 256;
  const int packNB = (33 * 2048 + 255) / 256;

  hipMemsetAsync(hist, 0, (size_t)NKEYS * 4, stream);
  k_pre<<<convNB + packNB, 256, 0, stream>>>(x, W, Wroot, xb, wp, wrootp, n4, convNB);
  k_hist<<<(E + 255) / 256, 256, 0, stream>>>(ei, et, hist, E);
  k_scan_local<<<NB, 256, 0, stream>>>(hist, offs);
  k_scatter<<<(E + 255) / 256, 256, 0, stream>>>(ei, et, offs, sorted, E);
  k_batch<<<NB, 256, 0, stream>>>(xb, wp, wrootp, bias, sorted, offs, h, N);
  k_score<<<(T + 3) / 4, 256, 0, stream>>>(h, relE, headI, tailI, relI, out, T);
}

// Round 4
// 327.649 us; speedup vs baseline: 1.6432x; 1.2780x over previous
//
#include <hip/hip_runtime.h>
#include <hip/hip_bf16.h>

typedef unsigned int u32;
typedef unsigned short u16;
typedef short short8 __attribute__((ext_vector_type(8)));
typedef float f32x4 __attribute__((ext_vector_type(4)));

#define R_ 32
#define KEYS_PER_B 2048     // 4 wavegroups * 32 relations * 16 rows
#define SORT_STRIDE 1024    // fixed per-chunk slots in sorted[] (mean 767, +9 sigma)
#define CAP 16              // per-wave per-relation buffered edge gathers

static __device__ __forceinline__ u16 f2bf(float f) {
  u32 u = __float_as_uint(f);
  u = (u + 0x7FFFu + ((u >> 16) & 1u)) >> 16;   // RNE
  return (u16)u;
}
static __device__ __forceinline__ u32 pk2(float a, float b) {
  __hip_bfloat162 h2 = __float22bfloat162_rn(make_float2(a, b));
  union { __hip_bfloat162 h; u32 u; } cv; cv.h = h2; return cv.u;
}

// ---- fused: x fp32->bf16 convert  +  W/W_root pack into MFMA B-fragment order ----
__global__ void k_pre(const float* __restrict__ x, const float* __restrict__ W,
                      const float* __restrict__ Wroot, u16* __restrict__ xb,
                      u16* __restrict__ wp, u16* __restrict__ wrootp,
                      int n4, int convNB) {
  if ((int)blockIdx.x < convNB) {
    int i = blockIdx.x * 256 + threadIdx.x;
    if (i >= n4) return;
    const float4 f = ((const float4*)x)[i];
    u32 lo = (u32)f2bf(f.x) | ((u32)f2bf(f.y) << 16);
    u32 hi = (u32)f2bf(f.z) | ((u32)f2bf(f.w) << 16);
    ((uint2*)xb)[i] = make_uint2(lo, hi);
  } else {
    int tid = (blockIdx.x - convNB) * 256 + threadIdx.x;
    if (tid >= 33 * 2048) return;
    int lane = tid & 63;
    int ks = (tid >> 6) & 3;
    int ct = (tid >> 8) & 7;
    int rr = tid >> 11;
    int i0 = ks * 32 + (lane >> 4) * 8;
    int o  = ct * 16 + (lane & 15);
    const float* src = (rr < 32) ? (W + (size_t)rr * (128 * 128)) : Wroot;
    u16* dst = (rr < 32) ? (wp + ((size_t)((rr * 8 + ct) * 4 + ks) * 64 + lane) * 8)
                         : (wrootp + ((size_t)((ct * 4 + ks) * 64 + lane)) * 8);
#pragma unroll
    for (int j = 0; j < 8; ++j) dst[j] = f2bf(src[(size_t)(i0 + j) * 128 + o]);
  }
}

// key = (tile, wavegroup-of-16, relation, row-in-group)
static __device__ __forceinline__ int sort_key(int tgt, int r) {
  return (tgt >> 6) * KEYS_PER_B + ((tgt >> 4) & 3) * 512 + r * 16 + (tgt & 15);
}

// ---- histogram of sort keys ----
__global__ void k_hist(const int* __restrict__ ei, const int* __restrict__ et,
                       int* __restrict__ hist, int E) {
  int e = blockIdx.x * 256 + threadIdx.x;
  if (e >= E) return;
  atomicAdd(hist + sort_key(ei[E + e], et[e]), 1);
}

// ---- per-chunk exclusive scan (chunk = 2048 keys = one batch) ----
__global__ __launch_bounds__(256) void k_scan_local(const int* __restrict__ hist,
                                                    int* __restrict__ offs) {
  __shared__ int wsum[4];
  int b = blockIdx.x, t = threadIdx.x;
  size_t base = (size_t)b * KEYS_PER_B + (size_t)t * 8;
  int4 a = *(const int4*)(hist + base);
  int4 c = *(const int4*)(hist + base + 4);
  int v[8] = {a.x, a.y, a.z, a.w, c.x, c.y, c.z, c.w};
  int s = 0;
#pragma unroll
  for (int i = 0; i < 8; ++i) s += v[i];
  int lane = t & 63, w = t >> 6;
  int x = s;
#pragma unroll
  for (int off = 1; off < 64; off <<= 1) {
    int y = __shfl_up(x, off);
    if (lane >= off) x += y;
  }
  if (lane == 63) wsum[w] = x;
  __syncthreads();
  int wb = 0;
  for (int i = 0; i < w; ++i) wb += wsum[i];
  int ex = wb + x - s;
  int o[8];
#pragma unroll
  for (int i = 0; i < 8; ++i) { o[i] = ex; ex += v[i]; }
  *(int4*)(offs + base) = make_int4(o[0], o[1], o[2], o[3]);
  *(int4*)(offs + base + 4) = make_int4(o[4], o[5], o[6], o[7]);
}

// ---- scatter; offs[key] becomes per-key chunk-local END; sorted = src | row64<<16 ----
__global__ void k_scatter(const int* __restrict__ ei, const int* __restrict__ et,
                          int* __restrict__ offs, u32* __restrict__ sorted, int E) {
  int e = blockIdx.x * 256 + threadIdx.x;
  if (e >= E) return;
  int src = ei[e];
  int tgt = ei[E + e];
  int r = et[e];
  int p = atomicAdd(offs + sort_key(tgt, r), 1);
  if (p < SORT_STRIDE)
    sorted[(size_t)(tgt >> 6) * SORT_STRIDE + p] = (u32)src | ((u32)(tgt & 63) << 16);
}

// ---- main batch kernel ----
// Round-0 structure with a repaired schedule:
//  * raw s_barrier + lgkmcnt(0)-only waits (NO vmcnt drain at barriers: the
//    next-relation gathers stay in flight across the barrier; they target
//    private VGPRs so no cross-wave visibility is needed)
//  * bfr (W-fragment) loads issued FIRST in phase A, pinned by
//    sched_barrier(0): the MFMAs wait on a counted vmcnt that excludes the
//    younger gather loads
//  * srt edge-vector prefetched one relation ahead (evA=current, evB=next):
//    the srt->readlane->gather address chain is off the phase critical path
__global__ __launch_bounds__(256) void k_batch(
    const u16* __restrict__ xb, const u16* __restrict__ wp, const u16* __restrict__ wrootp,
    const float* __restrict__ bias, const u32* __restrict__ sorted,
    const int* __restrict__ offs, float* __restrict__ h, int N) {
  __shared__ u16 aggb[64 * 136];   // 17.4 KB
  const int b = blockIdx.x, t = threadIdx.x;
  const int lane = t & 63, w = t >> 6;
  const int m = lane & 15, q = lane >> 4;
  const int nb = b * 64;
  const int keyBase = b * KEYS_PER_B;
  const int wkBase = keyBase + w * 512;
  const u32* srt = sorted + (size_t)b * SORT_STRIDE;

  const int nEdge = offs[keyBase + KEYS_PER_B - 1];
  const int clampP = (nEdge > 0) ? nEdge - 1 : 0;
  int sCur = (w == 0) ? 0 : offs[wkBase - 1];   // start of relation 0 (chunk-local)
  int eCur = offs[wkBase + 15];                 // E[0]
  int eNext = offs[wkBase + 31];                // E[1]
  int eN2   = offs[wkBase + 47];                // E[2]

  // prologue: srt vectors for rel 0 and rel 1, gathers for rel 0
  u32 evA, evB;
  {
    int pc = sCur + m;
    if (pc > clampP) pc = clampP;
    evA = srt[pc];
    int pc1 = eCur + m;
    if (pc1 > clampP) pc1 = clampP;
    evB = srt[pc1];
  }
  u32 xv[CAP];
  {
    const int nB = min(eCur - sCur, CAP);
#pragma unroll
    for (int j = 0; j < CAP; ++j) {
      if (j < nB) {
        int e = __builtin_amdgcn_readlane((int)evA, j);
        xv[j] = *(const u32*)(xb + (size_t)(e & 0xFFFF) * 128 + 2 * lane);
      }
    }
  }

  const short8 zero8 = {0, 0, 0, 0, 0, 0, 0, 0};
  f32x4 acc[4][2];
#pragma unroll
  for (int rt = 0; rt < 4; ++rt)
#pragma unroll
    for (int c = 0; c < 2; ++c) acc[rt][c] = (f32x4){0.f, 0.f, 0.f, 0.f};
  const int wct0 = w * 2;

  // root GEMM: acc += x_batch @ W_root (overlaps rel-0 gathers)
#pragma unroll
  for (int ks = 0; ks < 4; ++ks) {
    const int kb = ks * 32 + q * 8;
    short8 af[4];
#pragma unroll
    for (int rt = 0; rt < 4; ++rt) {
      int node = nb + rt * 16 + m;
      af[rt] = (node < N) ? *(const short8*)(xb + (size_t)node * 128 + kb) : zero8;
    }
#pragma unroll
    for (int c = 0; c < 2; ++c) {
      short8 bf = *(const short8*)(wrootp + ((size_t)(((wct0 + c) * 4 + ks) * 64 + lane)) * 8);
#pragma unroll
      for (int rt = 0; rt < 4; ++rt)
        acc[rt][c] = __builtin_amdgcn_mfma_f32_16x16x32_bf16(af[rt], bf, acc[rt][c], 0, 0, 0);
    }
  }

  for (int r = 0; r < R_; ++r) {
    // ---- build(r): zero own rows, consume buffer with run detection ----
#pragma unroll
    for (int rr = 0; rr < 16; ++rr)
      *(u32*)(aggb + (size_t)(w * 16 + rr) * 136 + 2 * lane) = 0;

    {
      const int nB = min(eCur - sCur, CAP);
      int curRow = -1, rc = 0;
      float v0 = 0.f, v1 = 0.f;
#pragma unroll
      for (int j = 0; j < CAP; ++j) {
        if (j < nB) {
          int e = __builtin_amdgcn_readlane((int)evA, j);
          int tl = (e >> 16) & 63;
          if (tl != curRow) {
            if (rc > 0) {
              float sc = __builtin_amdgcn_rcpf((float)rc);
              *(u32*)(aggb + (size_t)curRow * 136 + 2 * lane) = pk2(v0 * sc, v1 * sc);
            }
            curRow = tl; v0 = 0.f; v1 = 0.f; rc = 0;
          }
          v0 += __uint_as_float(xv[j] << 16);
          v1 += __uint_as_float(xv[j] & 0xFFFF0000u);
          ++rc;
        }
      }
      // rare overflow tail (cnt > CAP): serial loads
      for (int p = sCur + CAP; p < eCur; ++p) {
        u32 e = srt[p];
        u32 xvv = *(const u32*)(xb + (size_t)(e & 0xFFFFu) * 128 + 2 * lane);
        int tl = (int)((e >> 16) & 63);
        if (tl != curRow) {
          if (rc > 0) {
            float sc = __builtin_amdgcn_rcpf((float)rc);
            *(u32*)(aggb + (size_t)curRow * 136 + 2 * lane) = pk2(v0 * sc, v1 * sc);
          }
          curRow = tl; v0 = 0.f; v1 = 0.f; rc = 0;
        }
        v0 += __uint_as_float(xvv << 16);
        v1 += __uint_as_float(xvv & 0xFFFF0000u);
        ++rc;
      }
      if (rc > 0) {
        float sc = __builtin_amdgcn_rcpf((float)rc);
        *(u32*)(aggb + (size_t)curRow * 136 + 2 * lane) = pk2(v0 * sc, v1 * sc);
      }
    }

    // barrier 1: LDS writes visible; NO vmcnt drain (raw s_barrier)
    asm volatile("s_waitcnt lgkmcnt(0)" ::: "memory");
    __builtin_amdgcn_sched_barrier(0);
    __builtin_amdgcn_s_barrier();
    __builtin_amdgcn_sched_barrier(0);

    // ---- phase A ----
    // (a) W fragments FIRST: oldest outstanding vmem -> MFMA waits only here
    short8 bfr[4][2];
#pragma unroll
    for (int ks = 0; ks < 4; ++ks)
#pragma unroll
      for (int c = 0; c < 2; ++c)
        bfr[ks][c] = *(const short8*)(wp + ((size_t)(((r * 8 + wct0 + c) * 4 + ks) * 64 + lane)) * 8);
    __builtin_amdgcn_sched_barrier(0);

    // (b) gathers for r+1 (prefetched evB), srt vector for r+2, offs for r+3
    if (r < R_ - 1) {
      const int sN = eCur;
      const int eN3 = (r < R_ - 3) ? offs[wkBase + (r + 3) * 16 + 15] : eN2;
      const int nBn = min(eNext - sN, CAP);
#pragma unroll
      for (int j = 0; j < CAP; ++j) {
        if (j < nBn) {
          int e = __builtin_amdgcn_readlane((int)evB, j);
          xv[j] = *(const u32*)(xb + (size_t)(e & 0xFFFF) * 128 + 2 * lane);
        }
      }
      u32 evC = evB;
      if (r < R_ - 2) {
        int pc = eNext + m;
        if (pc > clampP) pc = clampP;
        evC = srt[pc];
      }
      sCur = sN; eCur = eNext; eNext = eN2; eN2 = eN3;
      evA = evB; evB = evC;
    }

    // (c) GEMM(r): acc += agg @ W[r]
#pragma unroll
    for (int ks = 0; ks < 4; ++ks) {
      const int kb = ks * 32 + q * 8;
      short8 af[4];
#pragma unroll
      for (int rt = 0; rt < 4; ++rt)
        af[rt] = *(const short8*)(aggb + (size_t)(rt * 16 + m) * 136 + kb);
#pragma unroll
      for (int c = 0; c < 2; ++c)
#pragma unroll
        for (int rt = 0; rt < 4; ++rt)
          acc[rt][c] = __builtin_amdgcn_mfma_f32_16x16x32_bf16(af[rt], bfr[ks][c], acc[rt][c], 0, 0, 0);
    }

    // barrier 2: all waves done READING aggb before next zero-writes.
    // lgkmcnt(0) + sched_barrier pin ensures this wave's ds_reads completed
    // (rule: MFMAs must not sink past the barrier). Still no vmcnt drain ->
    // the r+1 gathers remain in flight across the barrier.
    asm volatile("s_waitcnt lgkmcnt(0)" ::: "memory");
    __builtin_amdgcn_sched_barrier(0);
    __builtin_amdgcn_s_barrier();
    __builtin_amdgcn_sched_barrier(0);
  }

  // ---- epilogue: bias + relu + store h (fp32) ----
#pragma unroll
  for (int c = 0; c < 2; ++c) {
    const int col = (wct0 + c) * 16 + m;
    const float bv = bias[col];
#pragma unroll
    for (int rt = 0; rt < 4; ++rt) {
#pragma unroll
      for (int g = 0; g < 4; ++g) {
        const int row = nb + rt * 16 + q * 4 + g;
        if (row < N) {
          float v = acc[rt][c][g] + bv;
          h[(size_t)row * 128 + col] = v > 0.f ? v : 0.f;
        }
      }
    }
  }
}

// ---- DistMult scoring: one wave per triplet, float2 loads ----
__global__ void k_score(const float* __restrict__ h, const float* __restrict__ rel_emb,
                        const int* __restrict__ head, const int* __restrict__ tail,
                        const int* __restrict__ rel, float* __restrict__ out, int T) {
  int lane = threadIdx.x & 63, w = threadIdx.x >> 6;
  int gid = blockIdx.x * 4 + w;
  if (gid >= T) return;
  const float2 h2 = *(const float2*)(h + (size_t)head[gid] * 128 + 2 * lane);
  const float2 t2 = *(const float2*)(h + (size_t)tail[gid] * 128 + 2 * lane);
  const float2 r2 = *(const float2*)(rel_emb + (size_t)rel[gid] * 128 + 2 * lane);
  float s = h2.x * r2.x * t2.x + h2.y * r2.y * t2.y;
#pragma unroll
  for (int off = 32; off > 0; off >>= 1) s += __shfl_down(s, off);
  if (lane == 0) out[gid] = s;
}

extern "C" void kernel_launch(void* const* d_in, const int* in_sizes, int n_in,
                              void* d_out, int out_size, void* d_ws, size_t ws_size,
                              hipStream_t stream) {
  const float* x     = (const float*)d_in[0];
  const float* W     = (const float*)d_in[1];
  const float* Wroot = (const float*)d_in[2];
  const float* bias  = (const float*)d_in[3];
  const float* relE  = (const float*)d_in[4];
  const int* ei      = (const int*)d_in[5];
  const int* et      = (const int*)d_in[6];
  const int* headI   = (const int*)d_in[7];
  const int* tailI   = (const int*)d_in[8];
  const int* relI    = (const int*)d_in[9];
  float* out = (float*)d_out;

  const int N = in_sizes[0] / 128;   // 50000
  const int E = in_sizes[6];         // 600000
  const int T = in_sizes[7];         // 8192
  const int NB = (N + 63) >> 6;      // 782
  const int NKEYS = NB * KEYS_PER_B;

  char* p = (char*)d_ws;
  auto alloc = [&](size_t bytes) -> void* {
    void* r = (void*)p;
    p += (bytes + 255) & ~(size_t)255;
    return r;
  };
  u16* xb     = (u16*)alloc((size_t)N * 128 * 2);        // 12.8 MB
  u16* wp     = (u16*)alloc((size_t)32 * 2048 * 8 * 2);  // 1 MB
  u16* wrootp = (u16*)alloc((size_t)2048 * 8 * 2);
  int* hist   = (int*)alloc((size_t)NKEYS * 4);          // 6.4 MB
  int* offs   = (int*)alloc((size_t)NKEYS * 4);          // 6.4 MB
  u32* sorted = (u32*)alloc((size_t)NB * SORT_STRIDE * 4); // 3.2 MB
  float* h    = (float*)alloc((size_t)N * 128 * 4);      // 25.6 MB

  const int n4 = N * 128 / 4;
  const int convNB = (n4 + 255) / 256;
  const int packNB = (33 * 2048 + 255) / 256;

  hipMemsetAsync(hist, 0, (size_t)NKEYS * 4, stream);
  k_pre<<<convNB + packNB, 256, 0, stream>>>(x, W, Wroot, xb, wp, wrootp, n4, convNB);
  k_hist<<<(E + 255) / 256, 256, 0, stream>>>(ei, et, hist, E);
  k_scan_local<<<NB, 256, 0, stream>>>(hist, offs);
  k_scatter<<<(E + 255) / 256, 256, 0, stream>>>(ei, et, offs, sorted, E);
  k_batch<<<NB, 256, 0, stream>>>(xb, wp, wrootp, bias, sorted, offs, h, N);
  k_score<<<(T + 3) / 4, 256, 0, stream>>>(h, relE, headI, tailI, relI, out, T);
}

// Round 5
// 319.424 us; speedup vs baseline: 1.6855x; 1.0258x over previous
//
#include <hip/hip_runtime.h>
#include <hip/hip_bf16.h>

typedef unsigned int u32;
typedef unsigned short u16;
typedef short short8 __attribute__((ext_vector_type(8)));
typedef float f32x4 __attribute__((ext_vector_type(4)));

#define R_ 32
#define KEYS_PER_B 2048     // 4 wavegroups * 32 relations * 16 rows
#define SORT_STRIDE 1024    // fixed per-chunk slots in sorted[] (mean 767, +9 sigma)
#define CAP 16              // per-wave per-relation buffered edge gathers

static __device__ __forceinline__ u16 f2bf(float f) {
  u32 u = __float_as_uint(f);
  u = (u + 0x7FFFu + ((u >> 16) & 1u)) >> 16;   // RNE
  return (u16)u;
}
static __device__ __forceinline__ u32 pk2(float a, float b) {
  __hip_bfloat162 h2 = __float22bfloat162_rn(make_float2(a, b));
  union { __hip_bfloat162 h; u32 u; } cv; cv.h = h2; return cv.u;
}

// key = (tile, wavegroup-of-16, relation, row-in-group)
static __device__ __forceinline__ int sort_key(int tgt, int r) {
  return (tgt >> 6) * KEYS_PER_B + ((tgt >> 4) & 3) * 512 + r * 16 + (tgt & 15);
}

// ---- fused: x fp32->bf16 convert + W pack (LDS transpose) + edge histogram ----
// Section 1 (convNB blocks): coalesced convert of x.
// Section 2 (33 blocks): one block per W[r] / Wroot. Coalesced float4 read ->
//   bf16 in LDS -> strided LDS reads (cheap) -> coalesced 16B packed stores.
//   Replaces the old 512B-strided 4B global reads (~16x line over-fetch).
// Section 3: histogram of sort keys (was kernel k_hist).
__global__ __launch_bounds__(256) void k_pre(
    const float* __restrict__ x, const float* __restrict__ W,
    const float* __restrict__ Wroot, u16* __restrict__ xb,
    u16* __restrict__ wp, u16* __restrict__ wrootp,
    const int* __restrict__ ei, const int* __restrict__ et, int* __restrict__ hist,
    int n4, int convNB, int E) {
  __shared__ u32 lds[8192];   // 32 KB: one 128x128 bf16 matrix
  int bx = blockIdx.x;
  const int t = threadIdx.x;
  if (bx < convNB) {
    int i = bx * 256 + t;
    if (i >= n4) return;
    const float4 f = ((const float4*)x)[i];
    u32 lo = (u32)f2bf(f.x) | ((u32)f2bf(f.y) << 16);
    u32 hi = (u32)f2bf(f.z) | ((u32)f2bf(f.w) << 16);
    ((uint2*)xb)[i] = make_uint2(lo, hi);
    return;
  }
  bx -= convNB;
  if (bx < 33) {
    const int rr = bx;
    const float* src = (rr < 32) ? (W + (size_t)rr * (128 * 128)) : Wroot;
#pragma unroll
    for (int k = 0; k < 16; ++k) {
      const int fi = k * 256 + t;
      const float4 f = ((const float4*)src)[fi];
      u32 lo = (u32)f2bf(f.x) | ((u32)f2bf(f.y) << 16);
      u32 hi = (u32)f2bf(f.z) | ((u32)f2bf(f.w) << 16);
      ((uint2*)lds)[fi] = make_uint2(lo, hi);
    }
    __syncthreads();
    const u16* l16 = (const u16*)lds;
#pragma unroll
    for (int p = 0; p < 8; ++p) {
      const int v = p * 256 + t;
      const int lane = v & 63, ks = (v >> 6) & 3, ct = v >> 8;
      const int i0 = ks * 32 + (lane >> 4) * 8;
      const int o  = ct * 16 + (lane & 15);
      u32 w01 = (u32)l16[(i0 + 0) * 128 + o] | ((u32)l16[(i0 + 1) * 128 + o] << 16);
      u32 w23 = (u32)l16[(i0 + 2) * 128 + o] | ((u32)l16[(i0 + 3) * 128 + o] << 16);
      u32 w45 = (u32)l16[(i0 + 4) * 128 + o] | ((u32)l16[(i0 + 5) * 128 + o] << 16);
      u32 w67 = (u32)l16[(i0 + 6) * 128 + o] | ((u32)l16[(i0 + 7) * 128 + o] << 16);
      u16* dst = (rr < 32) ? (wp + ((size_t)((rr * 8 + ct) * 4 + ks) * 64 + lane) * 8)
                           : (wrootp + ((size_t)((ct * 4 + ks) * 64 + lane)) * 8);
      *(uint4*)dst = make_uint4(w01, w23, w45, w67);
    }
    return;
  }
  bx -= 33;
  int e = bx * 256 + t;
  if (e >= E) return;
  atomicAdd(hist + sort_key(ei[E + e], et[e]), 1);
}

// ---- per-chunk exclusive scan (chunk = 2048 keys = one batch) ----
__global__ __launch_bounds__(256) void k_scan_local(const int* __restrict__ hist,
                                                    int* __restrict__ offs) {
  __shared__ int wsum[4];
  int b = blockIdx.x, t = threadIdx.x;
  size_t base = (size_t)b * KEYS_PER_B + (size_t)t * 8;
  int4 a = *(const int4*)(hist + base);
  int4 c = *(const int4*)(hist + base + 4);
  int v[8] = {a.x, a.y, a.z, a.w, c.x, c.y, c.z, c.w};
  int s = 0;
#pragma unroll
  for (int i = 0; i < 8; ++i) s += v[i];
  int lane = t & 63, w = t >> 6;
  int x = s;
#pragma unroll
  for (int off = 1; off < 64; off <<= 1) {
    int y = __shfl_up(x, off);
    if (lane >= off) x += y;
  }
  if (lane == 63) wsum[w] = x;
  __syncthreads();
  int wb = 0;
  for (int i = 0; i < w; ++i) wb += wsum[i];
  int ex = wb + x - s;
  int o[8];
#pragma unroll
  for (int i = 0; i < 8; ++i) { o[i] = ex; ex += v[i]; }
  *(int4*)(offs + base) = make_int4(o[0], o[1], o[2], o[3]);
  *(int4*)(offs + base + 4) = make_int4(o[4], o[5], o[6], o[7]);
}

// ---- scatter; offs[key] becomes per-key chunk-local END; sorted = src | row64<<16 ----
__global__ void k_scatter(const int* __restrict__ ei, const int* __restrict__ et,
                          int* __restrict__ offs, u32* __restrict__ sorted, int E) {
  int e = blockIdx.x * 256 + threadIdx.x;
  if (e >= E) return;
  int src = ei[e];
  int tgt = ei[E + e];
  int r = et[e];
  int p = atomicAdd(offs + sort_key(tgt, r), 1);
  if (p < SORT_STRIDE)
    sorted[(size_t)(tgt >> 6) * SORT_STRIDE + p] = (u32)src | ((u32)(tgt & 63) << 16);
}

// ---- main batch kernel: DEPTH-2 gather pipeline ----
// Structure of round 0/4 plus:
//  * xvA/xvB double buffer: gathers for relation r+2 are issued at phase r
//    -> ~1.5 phases of slack (vs <0.5) covers the ~900cy HBM-miss latency of
//    the random 256B gathers. Manual 2-unroll keeps all indexing static.
//  * all 32 per-relation end-offsets loaded ONCE into a lane-indexed register
//    (eAll) and extracted by readlane -> no offs loads inside the loop.
//  * raw s_barrier + lgkmcnt(0)-only waits: gathers (private VGPR dest)
//    stay in flight across barriers; no vmcnt drain anywhere in the loop.
#define PHASE(RR, XV, EVB)                                                     \
  {                                                                            \
    const int r = (RR);                                                        \
    const int Er = __builtin_amdgcn_readlane(eAll, r);                         \
    _Pragma("unroll") for (int rr = 0; rr < 16; ++rr)                          \
        *(u32*)(aggb + (size_t)(w * 16 + rr) * 136 + 2 * lane) = 0;            \
    {                                                                          \
      const int nB = min(Er - sCur, CAP);                                      \
      int curRow = -1, rc = 0;                                                 \
      float v0 = 0.f, v1 = 0.f;                                                \
      _Pragma("unroll") for (int j = 0; j < CAP; ++j) {                        \
        if (j < nB) {                                                          \
          int e = __builtin_amdgcn_readlane((int)(EVB), j);                    \
          int tl = (e >> 16) & 63;                                             \
          if (tl != curRow) {                                                  \
            if (rc > 0) {                                                      \
              float sc = __builtin_amdgcn_rcpf((float)rc);                     \
              *(u32*)(aggb + (size_t)curRow * 136 + 2 * lane) =                \
                  pk2(v0 * sc, v1 * sc);                                       \
            }                                                                  \
            curRow = tl; v0 = 0.f; v1 = 0.f; rc = 0;                           \
          }                                                                    \
          v0 += __uint_as_float((XV)[j] << 16);                                \
          v1 += __uint_as_float((XV)[j] & 0xFFFF0000u);                        \
          ++rc;                                                                \
        }                                                                      \
      }                                                                        \
      for (int p = sCur + CAP; p < Er; ++p) {                                  \
        u32 e = srt[p];                                                        \
        u32 xvv = *(const u32*)(xb + (size_t)(e & 0xFFFFu) * 128 + 2 * lane);  \
        int tl = (int)((e >> 16) & 63);                                        \
        if (tl != curRow) {                                                    \
          if (rc > 0) {                                                        \
            float sc = __builtin_amdgcn_rcpf((float)rc);                       \
            *(u32*)(aggb + (size_t)curRow * 136 + 2 * lane) =                  \
                pk2(v0 * sc, v1 * sc);                                         \
          }                                                                    \
          curRow = tl; v0 = 0.f; v1 = 0.f; rc = 0;                             \
        }                                                                      \
        v0 += __uint_as_float(xvv << 16);                                      \
        v1 += __uint_as_float(xvv & 0xFFFF0000u);                              \
        ++rc;                                                                  \
      }                                                                        \
      if (rc > 0) {                                                            \
        float sc = __builtin_amdgcn_rcpf((float)rc);                           \
        *(u32*)(aggb + (size_t)curRow * 136 + 2 * lane) =                      \
            pk2(v0 * sc, v1 * sc);                                             \
      }                                                                        \
    }                                                                          \
    asm volatile("s_waitcnt lgkmcnt(0)" ::: "memory");                         \
    __builtin_amdgcn_sched_barrier(0);                                         \
    __builtin_amdgcn_s_barrier();                                              \
    __builtin_amdgcn_sched_barrier(0);                                         \
    short8 bfr[4][2];                                                          \
    _Pragma("unroll") for (int ks = 0; ks < 4; ++ks)                           \
      _Pragma("unroll") for (int c = 0; c < 2; ++c)                            \
        bfr[ks][c] = *(const short8*)(wp +                                     \
            ((size_t)(((r * 8 + wct0 + c) * 4 + ks) * 64 + lane)) * 8);        \
    __builtin_amdgcn_sched_barrier(0);                                         \
    if (r + 2 < R_) {                                                          \
      const int sN = __builtin_amdgcn_readlane(eAll, r + 1);                   \
      const int eN = __builtin_amdgcn_readlane(eAll, r + 2);                   \
      (EVB) = ev2;                                                             \
      const int nBn = min(eN - sN, CAP);                                       \
      _Pragma("unroll") for (int j = 0; j < CAP; ++j) {                        \
        if (j < nBn) {                                                         \
          int e = __builtin_amdgcn_readlane((int)(EVB), j);                    \
          (XV)[j] = *(const u32*)(xb + (size_t)(e & 0xFFFF) * 128 + 2 * lane); \
        }                                                                      \
      }                                                                        \
      if (r + 3 < R_) {                                                        \
        int pcn = eN + m;                                                      \
        if (pcn > clampP) pcn = clampP;                                        \
        ev2 = srt[pcn];                                                        \
      }                                                                        \
    }                                                                          \
    _Pragma("unroll") for (int ks = 0; ks < 4; ++ks) {                         \
      const int kb = ks * 32 + q * 8;                                          \
      short8 af[4];                                                            \
      _Pragma("unroll") for (int rt = 0; rt < 4; ++rt)                         \
        af[rt] = *(const short8*)(aggb + (size_t)(rt * 16 + m) * 136 + kb);    \
      _Pragma("unroll") for (int c = 0; c < 2; ++c)                            \
        _Pragma("unroll") for (int rt = 0; rt < 4; ++rt)                       \
          acc[rt][c] = __builtin_amdgcn_mfma_f32_16x16x32_bf16(                \
              af[rt], bfr[ks][c], acc[rt][c], 0, 0, 0);                        \
    }                                                                          \
    asm volatile("s_waitcnt lgkmcnt(0)" ::: "memory");                         \
    __builtin_amdgcn_sched_barrier(0);                                         \
    __builtin_amdgcn_s_barrier();                                              \
    __builtin_amdgcn_sched_barrier(0);                                         \
    sCur = Er;                                                                 \
  }

__global__ __launch_bounds__(256) void k_batch(
    const u16* __restrict__ xb, const u16* __restrict__ wp, const u16* __restrict__ wrootp,
    const float* __restrict__ bias, const u32* __restrict__ sorted,
    const int* __restrict__ offs, float* __restrict__ h, int N) {
  __shared__ u16 aggb[64 * 136];   // 17.4 KB
  const int b = blockIdx.x, t = threadIdx.x;
  const int lane = t & 63, w = t >> 6;
  const int m = lane & 15, q = lane >> 4;
  const int nb = b * 64;
  const int keyBase = b * KEYS_PER_B;
  const int wkBase = keyBase + w * 512;
  const u32* srt = sorted + (size_t)b * SORT_STRIDE;

  const int nEdge = offs[keyBase + KEYS_PER_B - 1];
  const int clampP = (nEdge > 0) ? nEdge - 1 : 0;
  // all 32 relation END offsets for this wave, lane-indexed (lane r holds E[r])
  const int eAll = offs[wkBase + (lane & 31) * 16 + 15];
  int sCur = (w == 0) ? 0 : offs[wkBase - 1];

  const int E0 = __builtin_amdgcn_readlane(eAll, 0);
  const int E1 = __builtin_amdgcn_readlane(eAll, 1);

  // prologue: srt vectors + gathers for relations 0 and 1, srt vector for 2
  u32 evBufA, evBufB, ev2;
  u32 xvA[CAP], xvB[CAP];
  {
    int pc = sCur + m;
    if (pc > clampP) pc = clampP;
    evBufA = srt[pc];
  }
  {
    const int nB = min(E0 - sCur, CAP);
#pragma unroll
    for (int j = 0; j < CAP; ++j) {
      if (j < nB) {
        int e = __builtin_amdgcn_readlane((int)evBufA, j);
        xvA[j] = *(const u32*)(xb + (size_t)(e & 0xFFFF) * 128 + 2 * lane);
      }
    }
  }
  {
    int pc = E0 + m;
    if (pc > clampP) pc = clampP;
    evBufB = srt[pc];
  }
  {
    const int nB = min(E1 - E0, CAP);
#pragma unroll
    for (int j = 0; j < CAP; ++j) {
      if (j < nB) {
        int e = __builtin_amdgcn_readlane((int)evBufB, j);
        xvB[j] = *(const u32*)(xb + (size_t)(e & 0xFFFF) * 128 + 2 * lane);
      }
    }
  }
  {
    int pc = E1 + m;
    if (pc > clampP) pc = clampP;
    ev2 = srt[pc];
  }

  const short8 zero8 = {0, 0, 0, 0, 0, 0, 0, 0};
  f32x4 acc[4][2];
#pragma unroll
  for (int rt = 0; rt < 4; ++rt)
#pragma unroll
    for (int c = 0; c < 2; ++c) acc[rt][c] = (f32x4){0.f, 0.f, 0.f, 0.f};
  const int wct0 = w * 2;

  // root GEMM: acc += x_batch @ W_root (overlaps prologue gathers)
#pragma unroll
  for (int ks = 0; ks < 4; ++ks) {
    const int kb = ks * 32 + q * 8;
    short8 af[4];
#pragma unroll
    for (int rt = 0; rt < 4; ++rt) {
      int node = nb + rt * 16 + m;
      af[rt] = (node < N) ? *(const short8*)(xb + (size_t)node * 128 + kb) : zero8;
    }
#pragma unroll
    for (int c = 0; c < 2; ++c) {
      short8 bf = *(const short8*)(wrootp + ((size_t)(((wct0 + c) * 4 + ks) * 64 + lane)) * 8);
#pragma unroll
      for (int rt = 0; rt < 4; ++rt)
        acc[rt][c] = __builtin_amdgcn_mfma_f32_16x16x32_bf16(af[rt], bf, acc[rt][c], 0, 0, 0);
    }
  }

  for (int r2 = 0; r2 < R_; r2 += 2) {
    PHASE(r2, xvA, evBufA)
    PHASE(r2 + 1, xvB, evBufB)
  }

  // ---- epilogue: bias + relu + store h (fp32) ----
#pragma unroll
  for (int c = 0; c < 2; ++c) {
    const int col = (wct0 + c) * 16 + m;
    const float bv = bias[col];
#pragma unroll
    for (int rt = 0; rt < 4; ++rt) {
#pragma unroll
      for (int g = 0; g < 4; ++g) {
        const int row = nb + rt * 16 + q * 4 + g;
        if (row < N) {
          float v = acc[rt][c][g] + bv;
          h[(size_t)row * 128 + col] = v > 0.f ? v : 0.f;
        }
      }
    }
  }
}

// ---- DistMult scoring: one wave per triplet, float2 loads ----
__global__ void k_score(const float* __restrict__ h, const float* __restrict__ rel_emb,
                        const int* __restrict__ head, const int* __restrict__ tail,
                        const int* __restrict__ rel, float* __restrict__ out, int T) {
  int lane = threadIdx.x & 63, w = threadIdx.x >> 6;
  int gid = blockIdx.x * 4 + w;
  if (gid >= T) return;
  const float2 h2 = *(const float2*)(h + (size_t)head[gid] * 128 + 2 * lane);
  const float2 t2 = *(const float2*)(h + (size_t)tail[gid] * 128 + 2 * lane);
  const float2 r2 = *(const float2*)(rel_emb + (size_t)rel[gid] * 128 + 2 * lane);
  float s = h2.x * r2.x * t2.x + h2.y * r2.y * t2.y;
#pragma unroll
  for (int off = 32; off > 0; off >>= 1) s += __shfl_down(s, off);
  if (lane == 0) out[gid] = s;
}

extern "C" void kernel_launch(void* const* d_in, const int* in_sizes, int n_in,
                              void* d_out, int out_size, void* d_ws, size_t ws_size,
                              hipStream_t stream) {
  const float* x     = (const float*)d_in[0];
  const float* W     = (const float*)d_in[1];
  const float* Wroot = (const float*)d_in[2];
  const float* bias  = (const float*)d_in[3];
  const float* relE  = (const float*)d_in[4];
  const int* ei      = (const int*)d_in[5];
  const int* et      = (const int*)d_in[6];
  const int* headI   = (const int*)d_in[7];
  const int* tailI   = (const int*)d_in[8];
  const int* relI    = (const int*)d_in[9];
  float* out = (float*)d_out;

  const int N = in_sizes[0] / 128;   // 50000
  const int E = in_sizes[6];         // 600000
  const int T = in_sizes[7];         // 8192
  const int NB = (N + 63) >> 6;      // 782
  const int NKEYS = NB * KEYS_PER_B;

  char* p = (char*)d_ws;
  auto alloc = [&](size_t bytes) -> void* {
    void* r = (void*)p;
    p += (bytes + 255) & ~(size_t)255;
    return r;
  };
  u16* xb     = (u16*)alloc((size_t)N * 128 * 2);        // 12.8 MB
  u16* wp     = (u16*)alloc((size_t)32 * 2048 * 8 * 2);  // 1 MB
  u16* wrootp = (u16*)alloc((size_t)2048 * 8 * 2);
  int* hist   = (int*)alloc((size_t)NKEYS * 4);          // 6.4 MB
  int* offs   = (int*)alloc((size_t)NKEYS * 4);          // 6.4 MB
  u32* sorted = (u32*)alloc((size_t)NB * SORT_STRIDE * 4); // 3.2 MB
  float* h    = (float*)alloc((size_t)N * 128 * 4);      // 25.6 MB

  const int n4 = N * 128 / 4;
  const int convNB = (n4 + 255) / 256;
  const int histNB = (E + 255) / 256;

  hipMemsetAsync(hist, 0, (size_t)NKEYS * 4, stream);
  k_pre<<<convNB + 33 + histNB, 256, 0, stream>>>(x, W, Wroot, xb, wp, wrootp,
                                                  ei, et, hist, n4, convNB, E);
  k_scan_local<<<NB, 256, 0, stream>>>(hist, offs);
  k_scatter<<<(E + 255) / 256, 256, 0, stream>>>(ei, et, offs, sorted, E);
  k_batch<<<NB, 256, 0, stream>>>(xb, wp, wrootp, bias, sorted, offs, h, N);
  k_score<<<(T + 3) / 4, 256, 0, stream>>>(h, relE, headI, tailI, relI, out, T);
}

// Round 6
// 211.248 us; speedup vs baseline: 2.5486x; 1.5121x over previous
//
#include <hip/hip_runtime.h>
#include <hip/hip_bf16.h>

typedef unsigned int u32;
typedef unsigned short u16;
typedef short short8 __attribute__((ext_vector_type(8)));
typedef float f32x4 __attribute__((ext_vector_type(4)));

#define R_ 32
#define KEYS_PER_B 2048     // 4 wavegroups * 32 relations * 16 rows
#define SORT_STRIDE 1024    // per-tile slots in sorted[] (mean ~768, +9 sigma)
#define CAP 16              // per-wave per-relation buffered edge gathers
#define MAXU 16384          // max unique scored nodes (2*T)

static __device__ __forceinline__ u16 f2bf(float f) {
  u32 u = __float_as_uint(f);
  u = (u + 0x7FFFu + ((u >> 16) & 1u)) >> 16;   // RNE
  return (u16)u;
}
static __device__ __forceinline__ u32 pk2(float a, float b) {
  __hip_bfloat162 h2 = __float22bfloat162_rn(make_float2(a, b));
  union { __hip_bfloat162 h; u32 u; } cv; cv.h = h2; return cv.u;
}

// key over COMPACT target ids: (tile, wavegroup-of-16, relation, row-in-group)
static __device__ __forceinline__ int sort_key(int ct, int r) {
  return (ct >> 6) * KEYS_PER_B + ((ct >> 4) & 3) * 512 + r * 16 + (ct & 15);
}

// ---- K1: x fp32->bf16 convert + W pack (LDS transpose) + mark used nodes ----
__global__ __launch_bounds__(256) void k_prep(
    const float* __restrict__ x, const float* __restrict__ W,
    const float* __restrict__ Wroot, u16* __restrict__ xb,
    u16* __restrict__ wp, u16* __restrict__ wrootp,
    const int* __restrict__ head, const int* __restrict__ tail,
    int* __restrict__ flags, int n4, int convNB, int T) {
  __shared__ u32 lds[8192];   // 32 KB: one 128x128 bf16 matrix
  int bx = blockIdx.x;
  const int t = threadIdx.x;
  if (bx < convNB) {
    int i = bx * 256 + t;
    if (i >= n4) return;
    const float4 f = ((const float4*)x)[i];
    u32 lo = (u32)f2bf(f.x) | ((u32)f2bf(f.y) << 16);
    u32 hi = (u32)f2bf(f.z) | ((u32)f2bf(f.w) << 16);
    ((uint2*)xb)[i] = make_uint2(lo, hi);
    return;
  }
  bx -= convNB;
  if (bx < 33) {
    const int rr = bx;
    const float* src = (rr < 32) ? (W + (size_t)rr * (128 * 128)) : Wroot;
#pragma unroll
    for (int k = 0; k < 16; ++k) {
      const int fi = k * 256 + t;
      const float4 f = ((const float4*)src)[fi];
      u32 lo = (u32)f2bf(f.x) | ((u32)f2bf(f.y) << 16);
      u32 hi = (u32)f2bf(f.z) | ((u32)f2bf(f.w) << 16);
      ((uint2*)lds)[fi] = make_uint2(lo, hi);
    }
    __syncthreads();
    const u16* l16 = (const u16*)lds;
#pragma unroll
    for (int p = 0; p < 8; ++p) {
      const int v = p * 256 + t;
      const int lane = v & 63, ks = (v >> 6) & 3, ct = v >> 8;
      const int i0 = ks * 32 + (lane >> 4) * 8;
      const int o  = ct * 16 + (lane & 15);
      u32 w01 = (u32)l16[(i0 + 0) * 128 + o] | ((u32)l16[(i0 + 1) * 128 + o] << 16);
      u32 w23 = (u32)l16[(i0 + 2) * 128 + o] | ((u32)l16[(i0 + 3) * 128 + o] << 16);
      u32 w45 = (u32)l16[(i0 + 4) * 128 + o] | ((u32)l16[(i0 + 5) * 128 + o] << 16);
      u32 w67 = (u32)l16[(i0 + 6) * 128 + o] | ((u32)l16[(i0 + 7) * 128 + o] << 16);
      u16* dst = (rr < 32) ? (wp + ((size_t)((rr * 8 + ct) * 4 + ks) * 64 + lane) * 8)
                           : (wrootp + ((size_t)((ct * 4 + ks) * 64 + lane)) * 8);
      *(uint4*)dst = make_uint4(w01, w23, w45, w67);
    }
    return;
  }
  bx -= 33;
  int i = bx * 256 + t;
  if (i >= 2 * T) return;
  int n = (i < T) ? head[i] : tail[i - T];
  flags[n] = 1;   // racy same-value stores: benign
}

// ---- K2: compact-id assignment (atomic ticket; order irrelevant) ----
__global__ __launch_bounds__(256) void k_map(const int* __restrict__ flags,
                                             int* __restrict__ map,
                                             int* __restrict__ inv,
                                             int* __restrict__ cnt, int N) {
  int n = blockIdx.x * 256 + threadIdx.x;
  if (n >= N) return;
  if (flags[n]) {
    int c = atomicAdd(cnt, 1);
    map[n] = c;
    inv[c] = n;
  } else {
    map[n] = -1;
  }
}

// ---- K3: histogram of sort keys over KEPT edges (target used) ----
__global__ void k_hist(const int* __restrict__ ei, const int* __restrict__ et,
                       const int* __restrict__ map, int* __restrict__ hist, int E) {
  int e = blockIdx.x * 256 + threadIdx.x;
  if (e >= E) return;
  int mt = map[ei[E + e]];
  if (mt >= 0) atomicAdd(hist + sort_key(mt, et[e]), 1);
}

// ---- K4: per-tile exclusive scan (2048 keys per tile) ----
__global__ __launch_bounds__(256) void k_scan_local(const int* __restrict__ hist,
                                                    int* __restrict__ offs) {
  __shared__ int wsum[4];
  int b = blockIdx.x, t = threadIdx.x;
  size_t base = (size_t)b * KEYS_PER_B + (size_t)t * 8;
  int4 a = *(const int4*)(hist + base);
  int4 c = *(const int4*)(hist + base + 4);
  int v[8] = {a.x, a.y, a.z, a.w, c.x, c.y, c.z, c.w};
  int s = 0;
#pragma unroll
  for (int i = 0; i < 8; ++i) s += v[i];
  int lane = t & 63, w = t >> 6;
  int x = s;
#pragma unroll
  for (int off = 1; off < 64; off <<= 1) {
    int y = __shfl_up(x, off);
    if (lane >= off) x += y;
  }
  if (lane == 63) wsum[w] = x;
  __syncthreads();
  int wb = 0;
  for (int i = 0; i < w; ++i) wb += wsum[i];
  int ex = wb + x - s;
  int o[8];
#pragma unroll
  for (int i = 0; i < 8; ++i) { o[i] = ex; ex += v[i]; }
  *(int4*)(offs + base) = make_int4(o[0], o[1], o[2], o[3]);
  *(int4*)(offs + base + 4) = make_int4(o[4], o[5], o[6], o[7]);
}

// ---- K5: scatter kept edges; offs[key] -> per-key tile-local END ----
__global__ void k_scatter(const int* __restrict__ ei, const int* __restrict__ et,
                          const int* __restrict__ map,
                          int* __restrict__ offs, u32* __restrict__ sorted, int E) {
  int e = blockIdx.x * 256 + threadIdx.x;
  if (e >= E) return;
  int mt = map[ei[E + e]];
  if (mt < 0) return;
  int src = ei[e];
  int p = atomicAdd(offs + sort_key(mt, et[e]), 1);
  if (p < SORT_STRIDE)
    sorted[(size_t)(mt >> 6) * SORT_STRIDE + p] = (u32)src | ((u32)(mt & 63) << 16);
}

// ---- K6: main batch kernel over COMPACT tiles (depth-2 gather pipeline) ----
#define PHASE(RR, XV, EVB)                                                     \
  {                                                                            \
    const int r = (RR);                                                        \
    const int Er = __builtin_amdgcn_readlane(eAll, r);                         \
    _Pragma("unroll") for (int rr = 0; rr < 16; ++rr)                          \
        *(u32*)(aggb + (size_t)(w * 16 + rr) * 136 + 2 * lane) = 0;            \
    {                                                                          \
      const int nB = min(Er - sCur, CAP);                                      \
      int curRow = -1, rc = 0;                                                 \
      float v0 = 0.f, v1 = 0.f;                                                \
      _Pragma("unroll") for (int j = 0; j < CAP; ++j) {                        \
        if (j < nB) {                                                          \
          int e = __builtin_amdgcn_readlane((int)(EVB), j);                    \
          int tl = (e >> 16) & 63;                                             \
          if (tl != curRow) {                                                  \
            if (rc > 0) {                                                      \
              float sc = __builtin_amdgcn_rcpf((float)rc);                     \
              *(u32*)(aggb + (size_t)curRow * 136 + 2 * lane) =                \
                  pk2(v0 * sc, v1 * sc);                                       \
            }                                                                  \
            curRow = tl; v0 = 0.f; v1 = 0.f; rc = 0;                           \
          }                                                                    \
          v0 += __uint_as_float((XV)[j] << 16);                                \
          v1 += __uint_as_float((XV)[j] & 0xFFFF0000u);                        \
          ++rc;                                                                \
        }                                                                      \
      }                                                                        \
      for (int p = sCur + CAP; p < Er; ++p) {                                  \
        u32 e = srt[p];                                                        \
        u32 xvv = *(const u32*)(xb + (size_t)(e & 0xFFFFu) * 128 + 2 * lane);  \
        int tl = (int)((e >> 16) & 63);                                        \
        if (tl != curRow) {                                                    \
          if (rc > 0) {                                                        \
            float sc = __builtin_amdgcn_rcpf((float)rc);                       \
            *(u32*)(aggb + (size_t)curRow * 136 + 2 * lane) =                  \
                pk2(v0 * sc, v1 * sc);                                         \
          }                                                                    \
          curRow = tl; v0 = 0.f; v1 = 0.f; rc = 0;                             \
        }                                                                      \
        v0 += __uint_as_float(xvv << 16);                                      \
        v1 += __uint_as_float(xvv & 0xFFFF0000u);                              \
        ++rc;                                                                  \
      }                                                                        \
      if (rc > 0) {                                                            \
        float sc = __builtin_amdgcn_rcpf((float)rc);                           \
        *(u32*)(aggb + (size_t)curRow * 136 + 2 * lane) =                      \
            pk2(v0 * sc, v1 * sc);                                             \
      }                                                                        \
    }                                                                          \
    asm volatile("s_waitcnt lgkmcnt(0)" ::: "memory");                         \
    __builtin_amdgcn_sched_barrier(0);                                         \
    __builtin_amdgcn_s_barrier();                                              \
    __builtin_amdgcn_sched_barrier(0);                                         \
    short8 bfr[4][2];                                                          \
    _Pragma("unroll") for (int ks = 0; ks < 4; ++ks)                           \
      _Pragma("unroll") for (int c = 0; c < 2; ++c)                            \
        bfr[ks][c] = *(const short8*)(wp +                                     \
            ((size_t)(((r * 8 + wct0 + c) * 4 + ks) * 64 + lane)) * 8);        \
    __builtin_amdgcn_sched_barrier(0);                                         \
    if (r + 2 < R_) {                                                          \
      const int sN = __builtin_amdgcn_readlane(eAll, r + 1);                   \
      const int eN = __builtin_amdgcn_readlane(eAll, r + 2);                   \
      (EVB) = ev2;                                                             \
      const int nBn = min(eN - sN, CAP);                                       \
      _Pragma("unroll") for (int j = 0; j < CAP; ++j) {                        \
        if (j < nBn) {                                                         \
          int e = __builtin_amdgcn_readlane((int)(EVB), j);                    \
          (XV)[j] = *(const u32*)(xb + (size_t)(e & 0xFFFF) * 128 + 2 * lane); \
        }                                                                      \
      }                                                                        \
      if (r + 3 < R_) {                                                        \
        int pcn = eN + m;                                                      \
        if (pcn > clampP) pcn = clampP;                                        \
        ev2 = srt[pcn];                                                        \
      }                                                                        \
    }                                                                          \
    _Pragma("unroll") for (int ks = 0; ks < 4; ++ks) {                         \
      const int kb = ks * 32 + q * 8;                                          \
      short8 af[4];                                                            \
      _Pragma("unroll") for (int rt = 0; rt < 4; ++rt)                         \
        af[rt] = *(const short8*)(aggb + (size_t)(rt * 16 + m) * 136 + kb);    \
      _Pragma("unroll") for (int c = 0; c < 2; ++c)                            \
        _Pragma("unroll") for (int rt = 0; rt < 4; ++rt)                       \
          acc[rt][c] = __builtin_amdgcn_mfma_f32_16x16x32_bf16(                \
              af[rt], bfr[ks][c], acc[rt][c], 0, 0, 0);                        \
    }                                                                          \
    asm volatile("s_waitcnt lgkmcnt(0)" ::: "memory");                         \
    __builtin_amdgcn_sched_barrier(0);                                         \
    __builtin_amdgcn_s_barrier();                                              \
    __builtin_amdgcn_sched_barrier(0);                                         \
    sCur = Er;                                                                 \
  }

__global__ __launch_bounds__(256) void k_batch(
    const u16* __restrict__ xb, const u16* __restrict__ wp, const u16* __restrict__ wrootp,
    const float* __restrict__ bias, const u32* __restrict__ sorted,
    const int* __restrict__ offs, const int* __restrict__ inv,
    const int* __restrict__ cnt, float* __restrict__ h) {
  __shared__ u16 aggb[64 * 136];   // 17.4 KB
  const int nUsed = cnt[0];
  const int b = blockIdx.x, t = threadIdx.x;
  const int nb = b * 64;
  if (nb >= nUsed) return;         // uniform: before any barrier
  const int lane = t & 63, w = t >> 6;
  const int m = lane & 15, q = lane >> 4;
  const int keyBase = b * KEYS_PER_B;
  const int wkBase = keyBase + w * 512;
  const u32* srt = sorted + (size_t)b * SORT_STRIDE;

  const int nEdge = offs[keyBase + KEYS_PER_B - 1];
  const int clampP = (nEdge > 0) ? nEdge - 1 : 0;
  const int eAll = offs[wkBase + (lane & 31) * 16 + 15];
  int sCur = (w == 0) ? 0 : offs[wkBase - 1];

  const int E0 = __builtin_amdgcn_readlane(eAll, 0);
  const int E1 = __builtin_amdgcn_readlane(eAll, 1);

  u32 evBufA, evBufB, ev2;
  u32 xvA[CAP], xvB[CAP];
  {
    int pc = sCur + m;
    if (pc > clampP) pc = clampP;
    evBufA = srt[pc];
  }
  {
    const int nB = min(E0 - sCur, CAP);
#pragma unroll
    for (int j = 0; j < CAP; ++j) {
      if (j < nB) {
        int e = __builtin_amdgcn_readlane((int)evBufA, j);
        xvA[j] = *(const u32*)(xb + (size_t)(e & 0xFFFF) * 128 + 2 * lane);
      }
    }
  }
  {
    int pc = E0 + m;
    if (pc > clampP) pc = clampP;
    evBufB = srt[pc];
  }
  {
    const int nB = min(E1 - E0, CAP);
#pragma unroll
    for (int j = 0; j < CAP; ++j) {
      if (j < nB) {
        int e = __builtin_amdgcn_readlane((int)evBufB, j);
        xvB[j] = *(const u32*)(xb + (size_t)(e & 0xFFFF) * 128 + 2 * lane);
      }
    }
  }
  {
    int pc = E1 + m;
    if (pc > clampP) pc = clampP;
    ev2 = srt[pc];
  }

  const short8 zero8 = {0, 0, 0, 0, 0, 0, 0, 0};
  f32x4 acc[4][2];
#pragma unroll
  for (int rt = 0; rt < 4; ++rt)
#pragma unroll
    for (int c = 0; c < 2; ++c) acc[rt][c] = (f32x4){0.f, 0.f, 0.f, 0.f};
  const int wct0 = w * 2;

  // root GEMM: acc += x[inv[compact rows]] @ W_root
  int nodeR[4]; bool vR[4];
#pragma unroll
  for (int rt = 0; rt < 4; ++rt) {
    int crow = nb + rt * 16 + m;
    vR[rt] = crow < nUsed;
    nodeR[rt] = inv[vR[rt] ? crow : (nUsed - 1)];
  }
#pragma unroll
  for (int ks = 0; ks < 4; ++ks) {
    const int kb = ks * 32 + q * 8;
    short8 af[4];
#pragma unroll
    for (int rt = 0; rt < 4; ++rt)
      af[rt] = vR[rt] ? *(const short8*)(xb + (size_t)nodeR[rt] * 128 + kb) : zero8;
#pragma unroll
    for (int c = 0; c < 2; ++c) {
      short8 bf = *(const short8*)(wrootp + ((size_t)(((wct0 + c) * 4 + ks) * 64 + lane)) * 8);
#pragma unroll
      for (int rt = 0; rt < 4; ++rt)
        acc[rt][c] = __builtin_amdgcn_mfma_f32_16x16x32_bf16(af[rt], bf, acc[rt][c], 0, 0, 0);
    }
  }

  for (int r2 = 0; r2 < R_; r2 += 2) {
    PHASE(r2, xvA, evBufA)
    PHASE(r2 + 1, xvB, evBufB)
  }

  // ---- epilogue: bias + relu + store h (compact rows, fp32) ----
#pragma unroll
  for (int c = 0; c < 2; ++c) {
    const int col = (wct0 + c) * 16 + m;
    const float bv = bias[col];
#pragma unroll
    for (int rt = 0; rt < 4; ++rt) {
#pragma unroll
      for (int g = 0; g < 4; ++g) {
        const int row = nb + rt * 16 + q * 4 + g;
        if (row < nUsed) {
          float v = acc[rt][c][g] + bv;
          h[(size_t)row * 128 + col] = v > 0.f ? v : 0.f;
        }
      }
    }
  }
}

// ---- K7: DistMult scoring via compact map ----
__global__ void k_score(const float* __restrict__ h, const float* __restrict__ rel_emb,
                        const int* __restrict__ map,
                        const int* __restrict__ head, const int* __restrict__ tail,
                        const int* __restrict__ rel, float* __restrict__ out, int T) {
  int lane = threadIdx.x & 63, w = threadIdx.x >> 6;
  int gid = blockIdx.x * 4 + w;
  if (gid >= T) return;
  const int hr = map[head[gid]];
  const int tr = map[tail[gid]];
  const float2 h2 = *(const float2*)(h + (size_t)hr * 128 + 2 * lane);
  const float2 t2 = *(const float2*)(h + (size_t)tr * 128 + 2 * lane);
  const float2 r2 = *(const float2*)(rel_emb + (size_t)rel[gid] * 128 + 2 * lane);
  float s = h2.x * r2.x * t2.x + h2.y * r2.y * t2.y;
#pragma unroll
  for (int off = 32; off > 0; off >>= 1) s += __shfl_down(s, off);
  if (lane == 0) out[gid] = s;
}

extern "C" void kernel_launch(void* const* d_in, const int* in_sizes, int n_in,
                              void* d_out, int out_size, void* d_ws, size_t ws_size,
                              hipStream_t stream) {
  const float* x     = (const float*)d_in[0];
  const float* W     = (const float*)d_in[1];
  const float* Wroot = (const float*)d_in[2];
  const float* bias  = (const float*)d_in[3];
  const float* relE  = (const float*)d_in[4];
  const int* ei      = (const int*)d_in[5];
  const int* et      = (const int*)d_in[6];
  const int* headI   = (const int*)d_in[7];
  const int* tailI   = (const int*)d_in[8];
  const int* relI    = (const int*)d_in[9];
  float* out = (float*)d_out;

  const int N = in_sizes[0] / 128;   // 50000
  const int E = in_sizes[6];         // 600000
  const int T = in_sizes[7];         // 8192
  const int NB2 = MAXU / 64;         // 256 compact tiles (worst case)
  const int NKEYS2 = NB2 * KEYS_PER_B;

  char* p = (char*)d_ws;
  auto alloc = [&](size_t bytes) -> void* {
    void* r = (void*)p;
    p += (bytes + 255) & ~(size_t)255;
    return r;
  };
  u16* xb     = (u16*)alloc((size_t)N * 128 * 2);          // 12.8 MB
  u16* wp     = (u16*)alloc((size_t)32 * 2048 * 8 * 2);    // 1 MB
  u16* wrootp = (u16*)alloc((size_t)2048 * 8 * 2);
  // zeroed region: hist + flags + cnt (one memset)
  char* z0    = p;
  int* hist   = (int*)alloc((size_t)NKEYS2 * 4);           // 2 MB
  int* flags  = (int*)alloc((size_t)N * 4);                // 0.2 MB
  int* cnt    = (int*)alloc(256);
  size_t zBytes = (size_t)(p - z0);
  int* map    = (int*)alloc((size_t)N * 4);                // 0.2 MB
  int* inv    = (int*)alloc((size_t)MAXU * 4);             // 64 KB
  int* offs   = (int*)alloc((size_t)NKEYS2 * 4);           // 2 MB
  u32* sorted = (u32*)alloc((size_t)NB2 * SORT_STRIDE * 4); // 1 MB
  float* h    = (float*)alloc((size_t)MAXU * 128 * 4);     // 8.4 MB

  const int n4 = N * 128 / 4;
  const int convNB = (n4 + 255) / 256;
  const int markNB = (2 * T + 255) / 256;

  hipMemsetAsync(z0, 0, zBytes, stream);
  k_prep<<<convNB + 33 + markNB, 256, 0, stream>>>(x, W, Wroot, xb, wp, wrootp,
                                                   headI, tailI, flags, n4, convNB, T);
  k_map<<<(N + 255) / 256, 256, 0, stream>>>(flags, map, inv, cnt, N);
  k_hist<<<(E + 255) / 256, 256, 0, stream>>>(ei, et, map, hist, E);
  k_scan_local<<<NB2, 256, 0, stream>>>(hist, offs);
  k_scatter<<<(E + 255) / 256, 256, 0, stream>>>(ei, et, map, offs, sorted, E);
  k_batch<<<NB2, 256, 0, stream>>>(xb, wp, wrootp, bias, sorted, offs, inv, cnt, h);
  k_score<<<(T + 3) / 4, 256, 0, stream>>>(h, relE, map, headI, tailI, relI, out, T);
}

// Round 7
// 188.788 us; speedup vs baseline: 2.8518x; 1.1190x over previous
//
#include <hip/hip_runtime.h>
#include <hip/hip_bf16.h>

typedef unsigned int u32;
typedef unsigned short u16;
typedef short short8 __attribute__((ext_vector_type(8)));
typedef float f32x4 __attribute__((ext_vector_type(4)));

#define R_ 32
#define KEYS_PER_B 2048     // 4 wavegroups * 32 relations * 16 rows
#define SORT_STRIDE 1024    // per-tile slots in sorted[] (mean ~768, +9 sigma)
#define CAP 16              // per-wave per-relation buffered edge gathers
#define MAXU 16384          // max unique scored nodes (2*T)
#define NSPLIT 4            // relation-group split (4 blocks/CU fits 88 VGPR)
#define NRG 8               // relations per group (R_/NSPLIT)

static __device__ __forceinline__ u16 f2bf(float f) {
  u32 u = __float_as_uint(f);
  u = (u + 0x7FFFu + ((u >> 16) & 1u)) >> 16;   // RNE
  return (u16)u;
}
static __device__ __forceinline__ u32 pk2(float a, float b) {
  __hip_bfloat162 h2 = __float22bfloat162_rn(make_float2(a, b));
  union { __hip_bfloat162 h; u32 u; } cv; cv.h = h2; return cv.u;
}

// key over COMPACT target ids: (tile, wavegroup-of-16, relation, row-in-group)
static __device__ __forceinline__ int sort_key(int ct, int r) {
  return (ct >> 6) * KEYS_PER_B + ((ct >> 4) & 3) * 512 + r * 16 + (ct & 15);
}

// ---- K1: x convert + W pack (LDS transpose) + hist zero + mark/compact ----
// map must be pre-filled with -1 (0xFF memset), cnt with -1.
// Mark section: CAS ticket assigns compact ids directly (k_map eliminated).
__global__ __launch_bounds__(256) void k_prep(
    const float* __restrict__ x, const float* __restrict__ W,
    const float* __restrict__ Wroot, u16* __restrict__ xb,
    u16* __restrict__ wp, u16* __restrict__ wrootp,
    const int* __restrict__ head, const int* __restrict__ tail,
    int* __restrict__ map, int* __restrict__ inv, int* __restrict__ cnt,
    int* __restrict__ hist, int n4, int convNB, int histZB, int T) {
  __shared__ u32 lds[8192];   // 32 KB: one 128x128 bf16 matrix
  int bx = blockIdx.x;
  const int t = threadIdx.x;
  if (bx < convNB) {
    int i = bx * 256 + t;
    if (i >= n4) return;
    const float4 f = ((const float4*)x)[i];
    u32 lo = (u32)f2bf(f.x) | ((u32)f2bf(f.y) << 16);
    u32 hi = (u32)f2bf(f.z) | ((u32)f2bf(f.w) << 16);
    ((uint2*)xb)[i] = make_uint2(lo, hi);
    return;
  }
  bx -= convNB;
  if (bx < 33) {
    const int rr = bx;
    const float* src = (rr < 32) ? (W + (size_t)rr * (128 * 128)) : Wroot;
#pragma unroll
    for (int k = 0; k < 16; ++k) {
      const int fi = k * 256 + t;
      const float4 f = ((const float4*)src)[fi];
      u32 lo = (u32)f2bf(f.x) | ((u32)f2bf(f.y) << 16);
      u32 hi = (u32)f2bf(f.z) | ((u32)f2bf(f.w) << 16);
      ((uint2*)lds)[fi] = make_uint2(lo, hi);
    }
    __syncthreads();
    const u16* l16 = (const u16*)lds;
#pragma unroll
    for (int p = 0; p < 8; ++p) {
      const int v = p * 256 + t;
      const int lane = v & 63, ks = (v >> 6) & 3, ct = v >> 8;
      const int i0 = ks * 32 + (lane >> 4) * 8;
      const int o  = ct * 16 + (lane & 15);
      u32 w01 = (u32)l16[(i0 + 0) * 128 + o] | ((u32)l16[(i0 + 1) * 128 + o] << 16);
      u32 w23 = (u32)l16[(i0 + 2) * 128 + o] | ((u32)l16[(i0 + 3) * 128 + o] << 16);
      u32 w45 = (u32)l16[(i0 + 4) * 128 + o] | ((u32)l16[(i0 + 5) * 128 + o] << 16);
      u32 w67 = (u32)l16[(i0 + 6) * 128 + o] | ((u32)l16[(i0 + 7) * 128 + o] << 16);
      u16* dst = (rr < 32) ? (wp + ((size_t)((rr * 8 + ct) * 4 + ks) * 64 + lane) * 8)
                           : (wrootp + ((size_t)((ct * 4 + ks) * 64 + lane)) * 8);
      *(uint4*)dst = make_uint4(w01, w23, w45, w67);
    }
    return;
  }
  bx -= 33;
  if (bx < histZB) {
    ((int4*)hist)[bx * 256 + t] = make_int4(0, 0, 0, 0);
    return;
  }
  bx -= histZB;
  int i = bx * 256 + t;
  if (i >= 2 * T) return;
  int n = (i < T) ? head[i] : tail[i - T];
  if (atomicCAS(map + n, -1, -2) == -1) {
    int c = atomicAdd(cnt, 1) + 1;   // cnt starts at -1 -> first ticket 0
    inv[c] = n;
    map[n] = c;                      // overwrites -2; read only next kernel
  }
}

// ---- K2: histogram of sort keys over KEPT edges (target used) ----
__global__ void k_hist(const int* __restrict__ ei, const int* __restrict__ et,
                       const int* __restrict__ map, int* __restrict__ hist, int E) {
  int e = blockIdx.x * 256 + threadIdx.x;
  if (e >= E) return;
  int mt = map[ei[E + e]];
  if (mt >= 0) atomicAdd(hist + sort_key(mt, et[e]), 1);
}

// ---- K3: per-tile exclusive scan (2048 keys per tile) ----
__global__ __launch_bounds__(256) void k_scan_local(const int* __restrict__ hist,
                                                    int* __restrict__ offs) {
  __shared__ int wsum[4];
  int b = blockIdx.x, t = threadIdx.x;
  size_t base = (size_t)b * KEYS_PER_B + (size_t)t * 8;
  int4 a = *(const int4*)(hist + base);
  int4 c = *(const int4*)(hist + base + 4);
  int v[8] = {a.x, a.y, a.z, a.w, c.x, c.y, c.z, c.w};
  int s = 0;
#pragma unroll
  for (int i = 0; i < 8; ++i) s += v[i];
  int lane = t & 63, w = t >> 6;
  int x = s;
#pragma unroll
  for (int off = 1; off < 64; off <<= 1) {
    int y = __shfl_up(x, off);
    if (lane >= off) x += y;
  }
  if (lane == 63) wsum[w] = x;
  __syncthreads();
  int wb = 0;
  for (int i = 0; i < w; ++i) wb += wsum[i];
  int ex = wb + x - s;
  int o[8];
#pragma unroll
  for (int i = 0; i < 8; ++i) { o[i] = ex; ex += v[i]; }
  *(int4*)(offs + base) = make_int4(o[0], o[1], o[2], o[3]);
  *(int4*)(offs + base + 4) = make_int4(o[4], o[5], o[6], o[7]);
}

// ---- K4: scatter kept edges; offs[key] -> per-key tile-local END ----
__global__ void k_scatter(const int* __restrict__ ei, const int* __restrict__ et,
                          const int* __restrict__ map,
                          int* __restrict__ offs, u32* __restrict__ sorted, int E) {
  int e = blockIdx.x * 256 + threadIdx.x;
  if (e >= E) return;
  int mt = map[ei[E + e]];
  if (mt < 0) return;
  int src = ei[e];
  int p = atomicAdd(offs + sort_key(mt, et[e]), 1);
  if (p < SORT_STRIDE)
    sorted[(size_t)(mt >> 6) * SORT_STRIDE + p] = (u32)src | ((u32)(mt & 63) << 16);
}

// ---- K5: main batch kernel, RELATION-SPLIT over compact tiles ----
// Block (b, qs): tile b (64 compact nodes), relations qs*8..qs*8+7.
// qs==0 also does root GEMM + bias. Output = RAW partial plane qs (no relu);
// k_score merges the 4 planes and applies relu. 1024 blocks -> 4 blocks/CU:
// 4 independent phase streams per CU overlap the ~6Kcy serial phase latency
// measured at 1 block/CU (round 6).
#define PHASE(RR, RI, XV, EVB)                                                 \
  {                                                                            \
    const int r = (RR);                                                        \
    const int Er = __builtin_amdgcn_readlane(eAll, r);                         \
    _Pragma("unroll") for (int rr = 0; rr < 16; ++rr)                          \
        *(u32*)(aggb + (size_t)(w * 16 + rr) * 136 + 2 * lane) = 0;            \
    {                                                                          \
      const int nB = min(Er - sCur, CAP);                                      \
      int curRow = -1, rc = 0;                                                 \
      float v0 = 0.f, v1 = 0.f;                                                \
      _Pragma("unroll") for (int j = 0; j < CAP; ++j) {                        \
        if (j < nB) {                                                          \
          int e = __builtin_amdgcn_readlane((int)(EVB), j);                    \
          int tl = (e >> 16) & 63;                                             \
          if (tl != curRow) {                                                  \
            if (rc > 0) {                                                      \
              float sc = __builtin_amdgcn_rcpf((float)rc);                     \
              *(u32*)(aggb + (size_t)curRow * 136 + 2 * lane) =                \
                  pk2(v0 * sc, v1 * sc);                                       \
            }                                                                  \
            curRow = tl; v0 = 0.f; v1 = 0.f; rc = 0;                           \
          }                                                                    \
          v0 += __uint_as_float((XV)[j] << 16);                                \
          v1 += __uint_as_float((XV)[j] & 0xFFFF0000u);                        \
          ++rc;                                                                \
        }                                                                      \
      }                                                                        \
      for (int p = sCur + CAP; p < Er; ++p) {                                  \
        u32 e = srt[p];                                                        \
        u32 xvv = *(const u32*)(xb + (size_t)(e & 0xFFFFu) * 128 + 2 * lane);  \
        int tl = (int)((e >> 16) & 63);                                        \
        if (tl != curRow) {                                                    \
          if (rc > 0) {                                                        \
            float sc = __builtin_amdgcn_rcpf((float)rc);                       \
            *(u32*)(aggb + (size_t)curRow * 136 + 2 * lane) =                  \
                pk2(v0 * sc, v1 * sc);                                         \
          }                                                                    \
          curRow = tl; v0 = 0.f; v1 = 0.f; rc = 0;                             \
        }                                                                      \
        v0 += __uint_as_float(xvv << 16);                                      \
        v1 += __uint_as_float(xvv & 0xFFFF0000u);                              \
        ++rc;                                                                  \
      }                                                                        \
      if (rc > 0) {                                                            \
        float sc = __builtin_amdgcn_rcpf((float)rc);                           \
        *(u32*)(aggb + (size_t)curRow * 136 + 2 * lane) =                      \
            pk2(v0 * sc, v1 * sc);                                             \
      }                                                                        \
    }                                                                          \
    asm volatile("s_waitcnt lgkmcnt(0)" ::: "memory");                         \
    __builtin_amdgcn_sched_barrier(0);                                         \
    __builtin_amdgcn_s_barrier();                                              \
    __builtin_amdgcn_sched_barrier(0);                                         \
    short8 bfr[4][2];                                                          \
    _Pragma("unroll") for (int ks = 0; ks < 4; ++ks)                           \
      _Pragma("unroll") for (int c = 0; c < 2; ++c)                            \
        bfr[ks][c] = *(const short8*)(wp +                                     \
            ((size_t)(((r * 8 + wct0 + c) * 4 + ks) * 64 + lane)) * 8);        \
    __builtin_amdgcn_sched_barrier(0);                                         \
    if ((RI) + 2 < NRG) {                                                      \
      const int sN = __builtin_amdgcn_readlane(eAll, r + 1);                   \
      const int eN = __builtin_amdgcn_readlane(eAll, r + 2);                   \
      (EVB) = ev2;                                                             \
      const int nBn = min(eN - sN, CAP);                                       \
      _Pragma("unroll") for (int j = 0; j < CAP; ++j) {                        \
        if (j < nBn) {                                                         \
          int e = __builtin_amdgcn_readlane((int)(EVB), j);                    \
          (XV)[j] = *(const u32*)(xb + (size_t)(e & 0xFFFF) * 128 + 2 * lane); \
        }                                                                      \
      }                                                                        \
      if ((RI) + 3 < NRG) {                                                    \
        int pcn = eN + m;                                                      \
        if (pcn > clampP) pcn = clampP;                                        \
        ev2 = srt[pcn];                                                        \
      }                                                                        \
    }                                                                          \
    _Pragma("unroll") for (int ks = 0; ks < 4; ++ks) {                         \
      const int kb = ks * 32 + q * 8;                                          \
      short8 af[4];                                                            \
      _Pragma("unroll") for (int rt = 0; rt < 4; ++rt)                         \
        af[rt] = *(const short8*)(aggb + (size_t)(rt * 16 + m) * 136 + kb);    \
      _Pragma("unroll") for (int c = 0; c < 2; ++c)                            \
        _Pragma("unroll") for (int rt = 0; rt < 4; ++rt)                       \
          acc[rt][c] = __builtin_amdgcn_mfma_f32_16x16x32_bf16(                \
              af[rt], bfr[ks][c], acc[rt][c], 0, 0, 0);                        \
    }                                                                          \
    asm volatile("s_waitcnt lgkmcnt(0)" ::: "memory");                         \
    __builtin_amdgcn_sched_barrier(0);                                         \
    __builtin_amdgcn_s_barrier();                                              \
    __builtin_amdgcn_sched_barrier(0);                                         \
    sCur = Er;                                                                 \
  }

__global__ __launch_bounds__(256) void k_batch(
    const u16* __restrict__ xb, const u16* __restrict__ wp, const u16* __restrict__ wrootp,
    const float* __restrict__ bias, const u32* __restrict__ sorted,
    const int* __restrict__ offs, const int* __restrict__ inv,
    const int* __restrict__ cnt, float* __restrict__ h) {
  __shared__ u16 aggb[64 * 136];   // 17.4 KB
  const int nUsed = cnt[0] + 1;    // cnt holds last ticket (init -1)
  const int qs = blockIdx.x & (NSPLIT - 1);
  const int b = blockIdx.x >> 2;
  const int t = threadIdx.x;
  const int nb = b * 64;
  if (nb >= nUsed) return;         // uniform: before any barrier
  const int r0 = qs * NRG;
  const int lane = t & 63, w = t >> 6;
  const int m = lane & 15, q = lane >> 4;
  const int keyBase = b * KEYS_PER_B;
  const int wkBase = keyBase + w * 512;
  const u32* srt = sorted + (size_t)b * SORT_STRIDE;

  const int nEdge = offs[keyBase + KEYS_PER_B - 1];
  const int clampP = (nEdge > 0) ? nEdge - 1 : 0;
  const int eAll = offs[wkBase + (lane & 31) * 16 + 15];   // lane r: end of rel r
  int sCur = (w == 0 && qs == 0) ? 0 : offs[wkBase + r0 * 16 - 1];

  const int E0 = __builtin_amdgcn_readlane(eAll, r0);
  const int E1 = __builtin_amdgcn_readlane(eAll, r0 + 1);

  u32 evBufA, evBufB, ev2;
  u32 xvA[CAP], xvB[CAP];
  {
    int pc = sCur + m;
    if (pc > clampP) pc = clampP;
    evBufA = srt[pc];
  }
  {
    const int nB = min(E0 - sCur, CAP);
#pragma unroll
    for (int j = 0; j < CAP; ++j) {
      if (j < nB) {
        int e = __builtin_amdgcn_readlane((int)evBufA, j);
        xvA[j] = *(const u32*)(xb + (size_t)(e & 0xFFFF) * 128 + 2 * lane);
      }
    }
  }
  {
    int pc = E0 + m;
    if (pc > clampP) pc = clampP;
    evBufB = srt[pc];
  }
  {
    const int nB = min(E1 - E0, CAP);
#pragma unroll
    for (int j = 0; j < CAP; ++j) {
      if (j < nB) {
        int e = __builtin_amdgcn_readlane((int)evBufB, j);
        xvB[j] = *(const u32*)(xb + (size_t)(e & 0xFFFF) * 128 + 2 * lane);
      }
    }
  }
  {
    int pc = E1 + m;
    if (pc > clampP) pc = clampP;
    ev2 = srt[pc];
  }

  const short8 zero8 = {0, 0, 0, 0, 0, 0, 0, 0};
  f32x4 acc[4][2];
#pragma unroll
  for (int rt = 0; rt < 4; ++rt)
#pragma unroll
    for (int c = 0; c < 2; ++c) acc[rt][c] = (f32x4){0.f, 0.f, 0.f, 0.f};
  const int wct0 = w * 2;

  // root GEMM only in plane 0: acc += x[inv[compact rows]] @ W_root
  if (qs == 0) {
    int nodeR[4]; bool vR[4];
#pragma unroll
    for (int rt = 0; rt < 4; ++rt) {
      int crow = nb + rt * 16 + m;
      vR[rt] = crow < nUsed;
      nodeR[rt] = inv[vR[rt] ? crow : (nUsed - 1)];
    }
#pragma unroll
    for (int ks = 0; ks < 4; ++ks) {
      const int kb = ks * 32 + q * 8;
      short8 af[4];
#pragma unroll
      for (int rt = 0; rt < 4; ++rt)
        af[rt] = vR[rt] ? *(const short8*)(xb + (size_t)nodeR[rt] * 128 + kb) : zero8;
#pragma unroll
      for (int c = 0; c < 2; ++c) {
        short8 bf = *(const short8*)(wrootp + ((size_t)(((wct0 + c) * 4 + ks) * 64 + lane)) * 8);
#pragma unroll
        for (int rt = 0; rt < 4; ++rt)
          acc[rt][c] = __builtin_amdgcn_mfma_f32_16x16x32_bf16(af[rt], bf, acc[rt][c], 0, 0, 0);
      }
    }
  }

  for (int ri = 0; ri < NRG; ri += 2) {
    PHASE(r0 + ri, ri, xvA, evBufA)
    PHASE(r0 + ri + 1, ri + 1, xvB, evBufB)
  }

  // ---- epilogue: (+bias in plane 0) store RAW partial plane (no relu) ----
  float* hq = h + (size_t)qs * MAXU * 128;
#pragma unroll
  for (int c = 0; c < 2; ++c) {
    const int col = (wct0 + c) * 16 + m;
    const float bv = (qs == 0) ? bias[col] : 0.f;
#pragma unroll
    for (int rt = 0; rt < 4; ++rt) {
#pragma unroll
      for (int g = 0; g < 4; ++g) {
        const int row = nb + rt * 16 + q * 4 + g;
        if (row < nUsed) hq[(size_t)row * 128 + col] = acc[rt][c][g] + bv;
      }
    }
  }
}

// ---- K6: DistMult scoring; merge 4 partial planes + relu ----
__global__ void k_score(const float* __restrict__ h, const float* __restrict__ rel_emb,
                        const int* __restrict__ map,
                        const int* __restrict__ head, const int* __restrict__ tail,
                        const int* __restrict__ rel, float* __restrict__ out, int T) {
  int lane = threadIdx.x & 63, w = threadIdx.x >> 6;
  int gid = blockIdx.x * 4 + w;
  if (gid >= T) return;
  const int hr = map[head[gid]];
  const int tr = map[tail[gid]];
  const size_t ho = (size_t)hr * 128 + 2 * lane;
  const size_t to = (size_t)tr * 128 + 2 * lane;
  float hx = 0.f, hy = 0.f, tx = 0.f, ty = 0.f;
#pragma unroll
  for (int s = 0; s < NSPLIT; ++s) {
    const float2 a = *(const float2*)(h + (size_t)s * (MAXU * 128) + ho);
    const float2 c = *(const float2*)(h + (size_t)s * (MAXU * 128) + to);
    hx += a.x; hy += a.y; tx += c.x; ty += c.y;
  }
  hx = hx > 0.f ? hx : 0.f;
  hy = hy > 0.f ? hy : 0.f;
  tx = tx > 0.f ? tx : 0.f;
  ty = ty > 0.f ? ty : 0.f;
  const float2 r2 = *(const float2*)(rel_emb + (size_t)rel[gid] * 128 + 2 * lane);
  float s = hx * r2.x * tx + hy * r2.y * ty;
#pragma unroll
  for (int off = 32; off > 0; off >>= 1) s += __shfl_down(s, off);
  if (lane == 0) out[gid] = s;
}

extern "C" void kernel_launch(void* const* d_in, const int* in_sizes, int n_in,
                              void* d_out, int out_size, void* d_ws, size_t ws_size,
                              hipStream_t stream) {
  const float* x     = (const float*)d_in[0];
  const float* W     = (const float*)d_in[1];
  const float* Wroot = (const float*)d_in[2];
  const float* bias  = (const float*)d_in[3];
  const float* relE  = (const float*)d_in[4];
  const int* ei      = (const int*)d_in[5];
  const int* et      = (const int*)d_in[6];
  const int* headI   = (const int*)d_in[7];
  const int* tailI   = (const int*)d_in[8];
  const int* relI    = (const int*)d_in[9];
  float* out = (float*)d_out;

  const int N = in_sizes[0] / 128;   // 50000
  const int E = in_sizes[6];         // 600000
  const int T = in_sizes[7];         // 8192
  const int NB2 = MAXU / 64;         // 256 compact tiles (worst case)
  const int NKEYS2 = NB2 * KEYS_PER_B;

  char* p = (char*)d_ws;
  auto alloc = [&](size_t bytes) -> void* {
    void* r = (void*)p;
    p += (bytes + 255) & ~(size_t)255;
    return r;
  };
  u16* xb     = (u16*)alloc((size_t)N * 128 * 2);           // 12.8 MB
  u16* wp     = (u16*)alloc((size_t)32 * 2048 * 8 * 2);     // 1 MB
  u16* wrootp = (u16*)alloc((size_t)2048 * 8 * 2);
  int* hist   = (int*)alloc((size_t)NKEYS2 * 4);            // 2 MB (zeroed in k_prep)
  int* map    = (int*)alloc((size_t)(N + 64) * 4);          // map + cnt, one 0xFF fill
  int* cnt    = map + N;
  int* inv    = (int*)alloc((size_t)MAXU * 4);              // 64 KB
  int* offs   = (int*)alloc((size_t)NKEYS2 * 4);            // 2 MB
  u32* sorted = (u32*)alloc((size_t)NB2 * SORT_STRIDE * 4); // 1 MB
  float* h    = (float*)alloc((size_t)NSPLIT * MAXU * 128 * 4); // 33.5 MB

  const int n4 = N * 128 / 4;
  const int convNB = (n4 + 255) / 256;
  const int histZB = NKEYS2 / 1024;          // int4 x 256 per block
  const int markNB = (2 * T + 255) / 256;

  hipMemsetAsync(map, 0xFF, (size_t)(N + 64) * 4, stream);   // map=-1, cnt=-1
  k_prep<<<convNB + 33 + histZB + markNB, 256, 0, stream>>>(
      x, W, Wroot, xb, wp, wrootp, headI, tailI, map, inv, cnt, hist,
      n4, convNB, histZB, T);
  k_hist<<<(E + 255) / 256, 256, 0, stream>>>(ei, et, map, hist, E);
  k_scan_local<<<NB2, 256, 0, stream>>>(hist, offs);
  k_scatter<<<(E + 255) / 256, 256, 0, stream>>>(ei, et, map, offs, sorted, E);
  k_batch<<<NB2 * NSPLIT, 256, 0, stream>>>(xb, wp, wrootp, bias, sorted, offs, inv, cnt, h);
  k_score<<<(T + 3) / 4, 256, 0, stream>>>(h, relE, map, headI, tailI, relI, out, T);
}